// Round 2
// baseline (880.224 us; speedup 1.0000x reference)
//
#include <hip/hip_runtime.h>
#include <cstdint>
#include <cstddef>

// Problem constants (fixed by the reference)
#define NATOMS 400000
#define NEDGES 1600000
#define NGRAPH 4096
#define F_INN  78
#define HDIM   128
#define FF0D   256
#define FF1D   128

typedef __attribute__((ext_vector_type(8))) short short8;   // 8 bf16 (4 VGPRs)
typedef __attribute__((ext_vector_type(4))) short short4v;  // 4 bf16 (8B store)
typedef __attribute__((ext_vector_type(4))) float f32x4;
typedef __attribute__((ext_vector_type(2))) float f32x2;

// f32 -> bf16 round-to-nearest-even (bit-level)
static __device__ __forceinline__ short f2bf(float f) {
    unsigned u = __builtin_bit_cast(unsigned, f);
    unsigned r = (u + 0x7fffu + ((u >> 16) & 1u)) >> 16;
    return (short)r;
}
static __device__ __forceinline__ float bf2f(unsigned short u) {
    return __builtin_bit_cast(float, ((unsigned)u) << 16);
}

// ---------------- degree + per-edge rank (atomic return value) ----------------
__global__ __launch_bounds__(256) void k_degi(const int* __restrict__ dst,
                                              int* __restrict__ deg,
                                              int* __restrict__ rank, int E) {
    int e = blockIdx.x * 256 + threadIdx.x;
    if (e < E) rank[e] = atomicAdd(&deg[dst[e]], 1);
}

// ---------------- exclusive scan over N ints (3 kernels, in-place) ----------------
// scan1 also emits dinv = rsqrt(deg+1) (deg still intact at entry)
__global__ __launch_bounds__(256) void k_scan1(int* __restrict__ data,
                                               int* __restrict__ blockSums,
                                               float* __restrict__ dinv, int n) {
    __shared__ int ts[256];
    const int base = blockIdx.x * 1024 + threadIdx.x * 4;
    int v[4];
    #pragma unroll
    for (int j = 0; j < 4; ++j) v[j] = (base + j < n) ? data[base + j] : 0;
    #pragma unroll
    for (int j = 0; j < 4; ++j)
        if (base + j < n) dinv[base + j] = rsqrtf((float)v[j] + 1.0f);
    const int tot = v[0] + v[1] + v[2] + v[3];
    ts[threadIdx.x] = tot;
    __syncthreads();
    #pragma unroll
    for (int off = 1; off < 256; off <<= 1) {
        int t = (threadIdx.x >= off) ? ts[threadIdx.x - off] : 0;
        __syncthreads();
        ts[threadIdx.x] += t;
        __syncthreads();
    }
    int run = ts[threadIdx.x] - tot;
    #pragma unroll
    for (int j = 0; j < 4; ++j) {
        if (base + j < n) data[base + j] = run;
        run += v[j];
    }
    if (threadIdx.x == 255) blockSums[blockIdx.x] = ts[255];
}

__global__ __launch_bounds__(512) void k_scan2(int* __restrict__ blockSums, int nb) {
    __shared__ int ts[512];
    int v = (threadIdx.x < nb) ? blockSums[threadIdx.x] : 0;
    ts[threadIdx.x] = v;
    __syncthreads();
    #pragma unroll
    for (int off = 1; off < 512; off <<= 1) {
        int t = (threadIdx.x >= off) ? ts[threadIdx.x - off] : 0;
        __syncthreads();
        ts[threadIdx.x] += t;
        __syncthreads();
    }
    if (threadIdx.x < nb) blockSums[threadIdx.x] = ts[threadIdx.x] - v;
}

__global__ __launch_bounds__(256) void k_scan3(int* __restrict__ data,
                                               const int* __restrict__ blockSums,
                                               int n, int total) {
    const int off = blockSums[blockIdx.x];
    const int base = blockIdx.x * 1024 + threadIdx.x * 4;
    #pragma unroll
    for (int j = 0; j < 4; ++j)
        if (base + j < n) data[base + j] += off;
    if (blockIdx.x == 0 && threadIdx.x == 0) data[n] = total;
}

// ---------------- CSR fill: atomic-free (pos = row_start[d] + rank[e]) ----------
__global__ __launch_bounds__(256) void k_fill(const int* __restrict__ src,
                                              const int* __restrict__ dst,
                                              const int* __restrict__ row_start,
                                              const int* __restrict__ rank,
                                              int2* __restrict__ csr_ev,
                                              const float* __restrict__ dinv, int E) {
    int e = blockIdx.x * 256 + threadIdx.x;
    if (e >= E) return;
    int d = dst[e];
    int s = src[e];
    int pos = row_start[d] + rank[e];
    float norm = dinv[s] * dinv[d];
    csr_ev[pos] = make_int2(s, __builtin_bit_cast(int, norm));
}

// ---------------- weight pack: W [KSRC][128] f32 -> MFMA A-fragment order bf16 ----
// A[feat][k]: lane&15 = feat-within-tile ct, k = kc*32 + (lane>>4)*8 + j
template<int KC, int KSRC>
__global__ __launch_bounds__(64) void k_packw(const float* __restrict__ W,
                                              short* __restrict__ wf) {
    int t = blockIdx.x * 64 + threadIdx.x;      // t = f*64 + lane
    int f = t >> 6, lane = t & 63;
    int ct = f / KC, kc = f % KC;
    int n  = ct * 16 + (lane & 15);
    int k0 = kc * 32 + (lane >> 4) * 8;
    short8 o;
    #pragma unroll
    for (int j = 0; j < 8; ++j) {
        int k = k0 + j;
        float v = (k < KSRC) ? W[(size_t)k * 128 + n] : 0.f;
        o[j] = f2bf(v);
    }
    *(short8*)(wf + (size_t)t * 8) = o;
}

// ---------------- persistent MFMA GEMM: out[M,128] = in[M,KSRC] @ W (bf16 out) ----
// 1024 blocks (4/CU, = the 16-wave/CU VGPR cap); weights staged to LDS once.
// 2x-unrolled ping-pong software pipeline, NO rotation copies: loads for tile
// t+1 are issued before tile t's MFMAs, so every wave keeps a full A-fragment
// load batch in flight across each compute block. For the f32 input path the
// f32->bf16 conversion is deferred to just-before-use (otherwise the cvt chain
// consumes the loads at issue time and the wave stalls before the MFMAs).
template<int KC, bool F32IN, int KSRC>
__global__ __launch_bounds__(256, 4) void k_gemm_mfma(
    const void* __restrict__ inv, const short* __restrict__ wfrag,
    short* __restrict__ outp, int M)
{
    constexpr int NFRAG = 8 * KC;               // fragments (ct x kc)
    __shared__ short lds_w[NFRAG * 64 * 8];     // KC=4: 32 KB, KC=3: 24 KB

    const int tid = threadIdx.x;
    // ---- stage weight fragments into LDS once ----
    #pragma unroll
    for (int it = 0; it < NFRAG * 64 / 256; ++it) {
        int t = it * 256 + tid;
        *(short8*)(lds_w + (size_t)t * 8) = *(const short8*)(wfrag + (size_t)t * 8);
    }
    __syncthreads();

    const int lane = tid & 63;
    const int m = lane & 15, q = lane >> 4;
    const int gw = blockIdx.x * 4 + (tid >> 6);     // global wave id
    const int NW = gridDim.x * 4;                   // total waves
    const int NTILE = M / 16;

    // compute one 16-row tile from fragments + store
    auto tile_mma = [&](int t, const short8* afr) {
        f32x4 acc[8];
        #pragma unroll
        for (int ct = 0; ct < 8; ++ct) acc[ct] = (f32x4){0.f, 0.f, 0.f, 0.f};
        #pragma unroll
        for (int kc = 0; kc < KC; ++kc)
            #pragma unroll
            for (int ct = 0; ct < 8; ++ct) {
                const short8 wv = *(const short8*)(lds_w + ((size_t)((ct * KC + kc) * 64 + lane)) * 8);
                acc[ct] = __builtin_amdgcn_mfma_f32_16x16x32_bf16(wv, afr[kc], acc[ct], 0, 0, 0);
            }
        // D[feat][node]: lane owns node (t*16+m), feats ct*16+q*4 .. +3
        const size_t nodeoff = (size_t)(t * 16 + m) * 128;
        #pragma unroll
        for (int ct = 0; ct < 8; ++ct) {
            short4v o;
            o.x = f2bf(acc[ct][0]);
            o.y = f2bf(acc[ct][1]);
            o.z = f2bf(acc[ct][2]);
            o.w = f2bf(acc[ct][3]);
            *(short4v*)(outp + nodeoff + ct * 16 + q * 4) = o;
        }
    };

    if constexpr (F32IN) {
        float rawA[KC][8], rawB[KC][8];
        short8 afr[KC];
        // issue the loads only — no consumer, stays in flight
        auto load_raw = [&](int tile, float (*raw)[8]) {
            const float* xr = (const float*)inv + (size_t)(tile * 16 + m) * KSRC;
            #pragma unroll
            for (int kc = 0; kc < KC; ++kc) {
                const int k0 = kc * 32 + q * 8;
                #pragma unroll
                for (int p = 0; p < 4; ++p) {
                    const int k = k0 + 2 * p;
                    if (k + 2 <= KSRC) {          // KSRC even: pairs never straddle
                        f32x2 tv = *(const f32x2*)(xr + k);
                        raw[kc][2 * p] = tv.x; raw[kc][2 * p + 1] = tv.y;
                    } else {
                        raw[kc][2 * p] = 0.f; raw[kc][2 * p + 1] = 0.f;
                    }
                }
            }
        };
        // convert just before use
        auto cvt = [&](float (*raw)[8]) {
            #pragma unroll
            for (int kc = 0; kc < KC; ++kc) {
                short8 a;
                #pragma unroll
                for (int j = 0; j < 8; ++j) a[j] = f2bf(raw[kc][j]);
                afr[kc] = a;
            }
        };

        load_raw(gw, rawA);
        int t = gw;
        for (; t + NW < NTILE; t += 2 * NW) {
            load_raw(t + NW, rawB);               // B in flight during A's compute
            cvt(rawA);
            tile_mma(t, afr);
            if (t + 2 * NW < NTILE) load_raw(t + 2 * NW, rawA);
            cvt(rawB);
            tile_mma(t + NW, afr);
        }
        if (t < NTILE) { cvt(rawA); tile_mma(t, afr); }
    } else {
        short8 fA[KC], fB[KC];
        auto load_to = [&](int tile, short8* b) {
            const short* xr = (const short*)inv + (size_t)(tile * 16 + m) * KSRC;
            #pragma unroll
            for (int kc = 0; kc < KC; ++kc)
                b[kc] = *(const short8*)(xr + kc * 32 + q * 8);
        };

        load_to(gw, fA);
        int t = gw;
        for (; t + NW < NTILE; t += 2 * NW) {
            load_to(t + NW, fB);                  // B in flight during A's compute
            tile_mma(t, fA);
            if (t + 2 * NW < NTILE) load_to(t + 2 * NW, fA);
            tile_mma(t + NW, fB);
        }
        if (t < NTILE) tile_mma(t, fA);
    }
}

// ---------------- gather aggregation, FEATURE-SPLIT (64 feats per pass) ----------
// Two sequential launches (half=0,1) keep the random-read hot set at 51.2 MB so
// re-reads hit the 256 MB L3 instead of HBM.
// 8 lanes/node, 32 nodes/block: each lane covers 8 feats (16B contiguous loads,
// 128B fully-used line per row read).
// POOL=false: out[n] = relu(bias + hw[n]*dinv^2 + sum_s hw[s]*norm) -> agg (bf16)
// POOL=true : same value, but instead of writing agg, block-reduce max per graph
//             (nodes are batch-sorted; <=2 graphs per 32-node block) and
//             atomicMax into pool (f32-as-int; valid since values >= 0).
template<bool POOL>
__global__ __launch_bounds__(256) void k_gather_half(
    const unsigned short* __restrict__ hw, unsigned short* __restrict__ agg,
    const int* __restrict__ row_start, const int2* __restrict__ csr_ev,
    const float* __restrict__ dinv, const float* __restrict__ bias,
    const int* __restrict__ batch, int* __restrict__ pool, int half)
{
    const int n  = blockIdx.x * 32 + (threadIdx.x >> 3);
    const int c8 = half * 64 + (threadIdx.x & 7) * 8;     // feature base
    const float dv = dinv[n];
    const float d2 = dv * dv;

    float acc[8];
    {
        const short8 sv = *(const short8*)(hw + (size_t)n * HDIM + c8);
        #pragma unroll
        for (int j = 0; j < 8; ++j)
            acc[j] = fmaf(bf2f((unsigned short)sv[j]), d2, bias[c8 + j]);
    }

    const int s0 = row_start[n], s1 = row_start[n + 1];
    int i = s0;
    for (; i + 3 < s1; i += 4) {
        const int2 e0 = csr_ev[i];
        const int2 e1 = csr_ev[i + 1];
        const int2 e2 = csr_ev[i + 2];
        const int2 e3 = csr_ev[i + 3];
        const short8 r0 = *(const short8*)(hw + (size_t)e0.x * HDIM + c8);
        const short8 r1 = *(const short8*)(hw + (size_t)e1.x * HDIM + c8);
        const short8 r2 = *(const short8*)(hw + (size_t)e2.x * HDIM + c8);
        const short8 r3 = *(const short8*)(hw + (size_t)e3.x * HDIM + c8);
        const float w0 = __builtin_bit_cast(float, e0.y);
        const float w1 = __builtin_bit_cast(float, e1.y);
        const float w2 = __builtin_bit_cast(float, e2.y);
        const float w3 = __builtin_bit_cast(float, e3.y);
        #pragma unroll
        for (int j = 0; j < 8; ++j) acc[j] = fmaf(bf2f((unsigned short)r0[j]), w0, acc[j]);
        #pragma unroll
        for (int j = 0; j < 8; ++j) acc[j] = fmaf(bf2f((unsigned short)r1[j]), w1, acc[j]);
        #pragma unroll
        for (int j = 0; j < 8; ++j) acc[j] = fmaf(bf2f((unsigned short)r2[j]), w2, acc[j]);
        #pragma unroll
        for (int j = 0; j < 8; ++j) acc[j] = fmaf(bf2f((unsigned short)r3[j]), w3, acc[j]);
    }
    for (; i < s1; ++i) {
        const int2 e0 = csr_ev[i];
        const short8 r0 = *(const short8*)(hw + (size_t)e0.x * HDIM + c8);
        const float w0 = __builtin_bit_cast(float, e0.y);
        #pragma unroll
        for (int j = 0; j < 8; ++j) acc[j] = fmaf(bf2f((unsigned short)r0[j]), w0, acc[j]);
    }

    if constexpr (!POOL) {
        short8 o;
        #pragma unroll
        for (int j = 0; j < 8; ++j) o[j] = f2bf(fmaxf(acc[j], 0.f));
        __builtin_nontemporal_store(o, (short8*)(agg + (size_t)n * HDIM + c8));
    } else {
        // ---- fused graph max-pool (replaces agg write + k_pool) ----
        // relu is implicit: invalid slots masked to 0 and pool init'd to 0.
        const int gbase = batch[blockIdx.x * 32];           // uniform broadcast
        const int glast = batch[blockIdx.x * 32 + 31];      // uniform broadcast
        const int idx   = batch[n] - gbase;                 // 0 or 1

        float red[2][8];
        #pragma unroll
        for (int s = 0; s < 2; ++s)
            #pragma unroll
            for (int j = 0; j < 8; ++j)
                red[s][j] = (idx == s) ? fmaxf(acc[j], 0.f) : 0.f;

        // butterfly max across the 8 node-slots of the wave (bits 3..5 of lane)
        #pragma unroll
        for (int msk = 8; msk <= 32; msk <<= 1)
            #pragma unroll
            for (int s = 0; s < 2; ++s)
                #pragma unroll
                for (int j = 0; j < 8; ++j)
                    red[s][j] = fmaxf(red[s][j], __shfl_xor(red[s][j], msk));

        __shared__ float sm[4][2][64];
        const int wid  = threadIdx.x >> 6;
        const int lane = threadIdx.x & 63;
        if (lane < 8) {
            #pragma unroll
            for (int s = 0; s < 2; ++s)
                #pragma unroll
                for (int j = 0; j < 8; ++j)
                    sm[wid][s][lane * 8 + j] = red[s][j];
        }
        __syncthreads();
        if (threadIdx.x < 128) {
            const int s = threadIdx.x >> 6;      // graph slot
            const int f = threadIdx.x & 63;      // feature within half
            if (s == 0 || glast != gbase) {
                float m = fmaxf(fmaxf(sm[0][s][f], sm[1][s][f]),
                                fmaxf(sm[2][s][f], sm[3][s][f]));
                atomicMax(pool + (size_t)(gbase + s) * HDIM + half * 64 + f,
                          __builtin_bit_cast(int, m));
            }
        }
    }
}

// ---------------- f32 register-blocked GEMM (FF head only, tiny) ----------------
template<int K, int NC, bool OUT_RELU_BIAS>
__global__ __launch_bounds__(256) void k_gemm(
    const float* __restrict__ in, const float* __restrict__ W,
    const float* __restrict__ out_bias, float* __restrict__ out0, int M)
{
    constexpr int BK = 32;
    constexpr int TC = NC / 8;
    constexpr int TR = 256 / TC;
    constexpr int ROWS = TR * 8;
    constexpr int XST = ROWS + 4;

    __shared__ float xs[BK][XST];
    __shared__ float ws[BK][NC];

    const int tid = threadIdx.x;
    const int tc  = tid % TC;
    const int tr  = tid / TC;
    const int row0 = blockIdx.x * ROWS;

    float acc[8][8];
    #pragma unroll
    for (int i = 0; i < 8; ++i)
        #pragma unroll
        for (int j = 0; j < 8; ++j) acc[i][j] = 0.f;

    for (int k0 = 0; k0 < K; k0 += BK) {
        {
            constexpr int TASKS = BK * NC / 4;
            #pragma unroll
            for (int it = 0; it < TASKS / 256; ++it) {
                int t  = it * 256 + tid;
                int wk = t / (NC / 4);
                int wc = (t % (NC / 4)) * 4;
                *(float4*)(&ws[wk][wc]) = *(const float4*)(W + (size_t)(k0 + wk) * NC + wc);
            }
        }
        {
            constexpr int TASKS = ROWS * BK / 4;
            #pragma unroll
            for (int it = 0; it < TASKS / 256; ++it) {
                int t   = it * 256 + tid;
                int r   = t / (BK / 4);
                int kq  = (t % (BK / 4)) * 4;
                float4 x4 = *(const float4*)(in + (size_t)(row0 + r) * K + k0 + kq);
                xs[kq + 0][r] = x4.x; xs[kq + 1][r] = x4.y;
                xs[kq + 2][r] = x4.z; xs[kq + 3][r] = x4.w;
            }
        }
        __syncthreads();
        #pragma unroll 8
        for (int kk = 0; kk < BK; ++kk) {
            float a[8], b[8];
            #pragma unroll
            for (int i = 0; i < 8; ++i) a[i] = xs[kk][tr * 8 + i];
            #pragma unroll
            for (int j = 0; j < 8; ++j) b[j] = ws[kk][tc * 8 + j];
            #pragma unroll
            for (int i = 0; i < 8; ++i)
                #pragma unroll
                for (int j = 0; j < 8; ++j)
                    acc[i][j] = fmaf(a[i], b[j], acc[i][j]);
        }
        __syncthreads();
    }

    #pragma unroll
    for (int i = 0; i < 8; ++i) {
        const int row = row0 + tr * 8 + i;
        #pragma unroll
        for (int jq = 0; jq < 2; ++jq) {
            const int col = tc * 8 + jq * 4;
            float4 v;
            v.x = acc[i][jq * 4 + 0]; v.y = acc[i][jq * 4 + 1];
            v.z = acc[i][jq * 4 + 2]; v.w = acc[i][jq * 4 + 3];
            if constexpr (OUT_RELU_BIAS) {
                const float4 bb = *(const float4*)(out_bias + col);
                v.x = fmaxf(v.x + bb.x, 0.f); v.y = fmaxf(v.y + bb.y, 0.f);
                v.z = fmaxf(v.z + bb.z, 0.f); v.w = fmaxf(v.w + bb.w, 0.f);
            }
            *(float4*)(out0 + (size_t)row * NC + col) = v;
        }
    }
}

extern "C" void kernel_launch(void* const* d_in, const int* in_sizes, int n_in,
                              void* d_out, int out_size, void* d_ws, size_t ws_size,
                              hipStream_t stream) {
    const float* x    = (const float*)d_in[0];
    const int*   ei   = (const int*)d_in[1];
    const int*   batch= (const int*)d_in[2];
    const float* W0   = (const float*)d_in[3];
    const float* b0   = (const float*)d_in[4];
    const float* W1   = (const float*)d_in[5];
    const float* b1   = (const float*)d_in[6];
    const float* Wf0  = (const float*)d_in[7];
    const float* bf0  = (const float*)d_in[8];
    const float* Wf1  = (const float*)d_in[9];
    const float* bf1  = (const float*)d_in[10];
    float* out = (float*)d_out;

    const int* srcI = ei;
    const int* dstI = ei + NEDGES;

    constexpr int SCAN_NBLK = (NATOMS + 1023) / 1024;   // 391

    // workspace layout — total ~227.2 MB (round-6 proven envelope).
    // rank ALIASES the start of aggB: rank's lifetime (degi -> fill) ends before the
    // first gather writes aggB. All blocks 64B-aligned.
    char* base = (char*)d_ws;
    unsigned short* hwA  = (unsigned short*)(base + 0);              // N*128 bf16 = 102,400,000
    unsigned short* aggB = (unsigned short*)(base + 102400000);      // N*128 bf16 = 102,400,000
    int*   rank      = (int*)(base + 102400000);                     // E ints (alias of aggB)
    float* dinv      = (float*)(base + 204800000);                   // N f32 = 1,600,000
    int*   row_start = (int*)(base + 206400000);                     // N+1 ints
    int2*  csr_ev    = (int2*)(base + 208000064);                    // E int2 = 12,800,000
    int*   blockSums = (int*)(base + 220800064);                     // 512 ints
    float* pool      = (float*)(base + 220802112);                   // G*128 f32 = 2,097,152
    float* ff0       = (float*)(base + 222899264);                   // G*256 f32 = 4,194,304
    short* wf0       = (short*)(base + 227093568);                   // 8*3*64*8 bf16 = 24,576 B
    short* wf1       = (short*)(base + 227118144);                   // 8*4*64*8 bf16 = 32,768 B

    // 1) degree (+rank) -> scan (+dinv) -> atomic-free CSR fill
    hipMemsetAsync(row_start, 0, (size_t)(NATOMS + 1) * sizeof(int), stream);
    hipMemsetAsync(pool, 0, (size_t)NGRAPH * HDIM * sizeof(float), stream);  // pool init (relu identity)
    k_degi<<<(NEDGES + 255) / 256, 256, 0, stream>>>(dstI, row_start, rank, NEDGES);
    k_scan1<<<SCAN_NBLK, 256, 0, stream>>>(row_start, blockSums, dinv, NATOMS);
    k_scan2<<<1, 512, 0, stream>>>(blockSums, SCAN_NBLK);
    k_scan3<<<SCAN_NBLK, 256, 0, stream>>>(row_start, blockSums, NATOMS, NEDGES);
    k_fill<<<(NEDGES + 255) / 256, 256, 0, stream>>>(srcI, dstI, row_start, rank,
                                                     csr_ev, dinv, NEDGES);

    // 2) pack weights into MFMA fragment order (bf16)
    k_packw<3, F_INN><<<8 * 3, 64, 0, stream>>>(W0, wf0);
    k_packw<4, HDIM><<<8 * 4, 64, 0, stream>>>(W1, wf1);

    // 3) layer 0: hw0 = x@W0 (bf16) ; gather -> relu(agg + b0) bf16
    //    gather runs as two sequential 64-feature passes (51.2 MB hot set -> L3-resident)
    k_gemm_mfma<3, true, F_INN><<<1024, 256, 0, stream>>>(x, wf0, (short*)hwA, NATOMS);
    k_gather_half<false><<<NATOMS / 32, 256, 0, stream>>>(hwA, aggB, row_start, csr_ev,
                                                          dinv, b0, nullptr, nullptr, 0);
    k_gather_half<false><<<NATOMS / 32, 256, 0, stream>>>(hwA, aggB, row_start, csr_ev,
                                                          dinv, b0, nullptr, nullptr, 1);

    // 4) layer 1: hw1 = h@W1 (bf16) ; gather fused with graph max-pool (no agg write)
    k_gemm_mfma<4, false, HDIM><<<1024, 256, 0, stream>>>(aggB, wf1, (short*)hwA, NATOMS);
    k_gather_half<true><<<NATOMS / 32, 256, 0, stream>>>(hwA, nullptr, row_start, csr_ev,
                                                         dinv, b1, batch, (int*)pool, 0);
    k_gather_half<true><<<NATOMS / 32, 256, 0, stream>>>(hwA, nullptr, row_start, csr_ev,
                                                         dinv, b1, batch, (int*)pool, 1);

    // 5) FF head (f32, tiny)
    k_gemm<HDIM, FF0D, true><<<NGRAPH / 64, 256, 0, stream>>>(pool, Wf0, bf0, ff0, NGRAPH);
    k_gemm<FF0D, FF1D, true><<<NGRAPH / 128, 256, 0, stream>>>(ff0, Wf1, bf1, out, NGRAPH);
}

// Round 3
// 678.631 us; speedup vs baseline: 1.2971x; 1.2971x over previous
//
#include <hip/hip_runtime.h>
#include <cstdint>
#include <cstddef>

// Problem constants (fixed by the reference)
#define NATOMS 400000
#define NEDGES 1600000
#define NGRAPH 4096
#define F_INN  78
#define HDIM   128
#define FF0D   256
#define FF1D   128

typedef __attribute__((ext_vector_type(8))) short short8;   // 8 bf16 (4 VGPRs)
typedef __attribute__((ext_vector_type(4))) short short4v;  // 4 bf16 (8B store)
typedef __attribute__((ext_vector_type(4))) float f32x4;
typedef __attribute__((ext_vector_type(2))) float f32x2;

// f32 -> bf16 round-to-nearest-even (bit-level)
static __device__ __forceinline__ short f2bf(float f) {
    unsigned u = __builtin_bit_cast(unsigned, f);
    unsigned r = (u + 0x7fffu + ((u >> 16) & 1u)) >> 16;
    return (short)r;
}
static __device__ __forceinline__ float bf2f(unsigned short u) {
    return __builtin_bit_cast(float, ((unsigned)u) << 16);
}

// ---------------- degree + per-edge rank (atomic return value) ----------------
__global__ __launch_bounds__(256) void k_degi(const int* __restrict__ dst,
                                              int* __restrict__ deg,
                                              int* __restrict__ rank, int E) {
    int e = blockIdx.x * 256 + threadIdx.x;
    if (e < E) rank[e] = atomicAdd(&deg[dst[e]], 1);
}

// ---------------- exclusive scan over N ints (3 kernels, in-place) ----------------
// scan1 also emits dinv = rsqrt(deg+1) (deg still intact at entry)
__global__ __launch_bounds__(256) void k_scan1(int* __restrict__ data,
                                               int* __restrict__ blockSums,
                                               float* __restrict__ dinv, int n) {
    __shared__ int ts[256];
    const int base = blockIdx.x * 1024 + threadIdx.x * 4;
    int v[4];
    #pragma unroll
    for (int j = 0; j < 4; ++j) v[j] = (base + j < n) ? data[base + j] : 0;
    #pragma unroll
    for (int j = 0; j < 4; ++j)
        if (base + j < n) dinv[base + j] = rsqrtf((float)v[j] + 1.0f);
    const int tot = v[0] + v[1] + v[2] + v[3];
    ts[threadIdx.x] = tot;
    __syncthreads();
    #pragma unroll
    for (int off = 1; off < 256; off <<= 1) {
        int t = (threadIdx.x >= off) ? ts[threadIdx.x - off] : 0;
        __syncthreads();
        ts[threadIdx.x] += t;
        __syncthreads();
    }
    int run = ts[threadIdx.x] - tot;
    #pragma unroll
    for (int j = 0; j < 4; ++j) {
        if (base + j < n) data[base + j] = run;
        run += v[j];
    }
    if (threadIdx.x == 255) blockSums[blockIdx.x] = ts[255];
}

__global__ __launch_bounds__(512) void k_scan2(int* __restrict__ blockSums, int nb) {
    __shared__ int ts[512];
    int v = (threadIdx.x < nb) ? blockSums[threadIdx.x] : 0;
    ts[threadIdx.x] = v;
    __syncthreads();
    #pragma unroll
    for (int off = 1; off < 512; off <<= 1) {
        int t = (threadIdx.x >= off) ? ts[threadIdx.x - off] : 0;
        __syncthreads();
        ts[threadIdx.x] += t;
        __syncthreads();
    }
    if (threadIdx.x < nb) blockSums[threadIdx.x] = ts[threadIdx.x] - v;
}

__global__ __launch_bounds__(256) void k_scan3(int* __restrict__ data,
                                               const int* __restrict__ blockSums,
                                               int n, int total) {
    const int off = blockSums[blockIdx.x];
    const int base = blockIdx.x * 1024 + threadIdx.x * 4;
    #pragma unroll
    for (int j = 0; j < 4; ++j)
        if (base + j < n) data[base + j] += off;
    if (blockIdx.x == 0 && threadIdx.x == 0) data[n] = total;
}

// ---------------- CSR fill: atomic-free (pos = row_start[d] + rank[e]) ----------
__global__ __launch_bounds__(256) void k_fill(const int* __restrict__ src,
                                              const int* __restrict__ dst,
                                              const int* __restrict__ row_start,
                                              const int* __restrict__ rank,
                                              int2* __restrict__ csr_ev,
                                              const float* __restrict__ dinv, int E) {
    int e = blockIdx.x * 256 + threadIdx.x;
    if (e >= E) return;
    int d = dst[e];
    int s = src[e];
    int pos = row_start[d] + rank[e];
    float norm = dinv[s] * dinv[d];
    csr_ev[pos] = make_int2(s, __builtin_bit_cast(int, norm));
}

// ---------------- weight pack: W [KSRC][128] f32 -> MFMA A-fragment order bf16 ----
// A[feat][k]: lane&15 = feat-within-tile ct, k = kc*32 + (lane>>4)*8 + j
template<int KC, int KSRC>
__global__ __launch_bounds__(64) void k_packw(const float* __restrict__ W,
                                              short* __restrict__ wf) {
    int t = blockIdx.x * 64 + threadIdx.x;      // t = f*64 + lane
    int f = t >> 6, lane = t & 63;
    int ct = f / KC, kc = f % KC;
    int n  = ct * 16 + (lane & 15);
    int k0 = kc * 32 + (lane >> 4) * 8;
    short8 o;
    #pragma unroll
    for (int j = 0; j < 8; ++j) {
        int k = k0 + j;
        float v = (k < KSRC) ? W[(size_t)k * 128 + n] : 0.f;
        o[j] = f2bf(v);
    }
    *(short8*)(wf + (size_t)t * 8) = o;
}

// ---------------- persistent MFMA GEMM: out[M,128] = in[M,KSRC] @ W (bf16 out) ----
// 768 blocks (3/CU at ~160 regs/wave incl. accumulator AGPRs — exactly resident,
// no tail). Weights staged to LDS once. Software pipeline WITHOUT forcing
// occupancy bounds (R1 lesson: launch_bounds min-waves + doubled staging buffers
// spilled to scratch, FETCH/WRITE tripled).
//   f32 path: single raw buffer; per iter: cvt(raw)->afr (consumes loads that
//   flew during the PREVIOUS tile's MFMAs), issue next loads into raw (no
//   consumer), then MFMA. Loads thus stay in flight across every MFMA block
//   at only +24 VGPR.
//   bf16 path: 1-deep prefetch into fB, MFMA from fA, copy fB->fA after MFMAs.
template<int KC, bool F32IN, int KSRC>
__global__ __launch_bounds__(256) void k_gemm_mfma(
    const void* __restrict__ inv, const short* __restrict__ wfrag,
    short* __restrict__ outp, int M)
{
    constexpr int NFRAG = 8 * KC;               // fragments (ct x kc)
    __shared__ short lds_w[NFRAG * 64 * 8];     // KC=4: 32 KB, KC=3: 24 KB

    const int tid = threadIdx.x;
    // ---- stage weight fragments into LDS once ----
    #pragma unroll
    for (int it = 0; it < NFRAG * 64 / 256; ++it) {
        int t = it * 256 + tid;
        *(short8*)(lds_w + (size_t)t * 8) = *(const short8*)(wfrag + (size_t)t * 8);
    }
    __syncthreads();

    const int lane = tid & 63;
    const int m = lane & 15, q = lane >> 4;
    const int gw = blockIdx.x * 4 + (tid >> 6);     // global wave id
    const int NW = gridDim.x * 4;                   // total waves
    const int NTILE = M / 16;

    // compute one 16-row tile from fragments + store
    auto tile_mma = [&](int t, const short8* afr) {
        f32x4 acc[8];
        #pragma unroll
        for (int ct = 0; ct < 8; ++ct) acc[ct] = (f32x4){0.f, 0.f, 0.f, 0.f};
        #pragma unroll
        for (int kc = 0; kc < KC; ++kc)
            #pragma unroll
            for (int ct = 0; ct < 8; ++ct) {
                const short8 wv = *(const short8*)(lds_w + ((size_t)((ct * KC + kc) * 64 + lane)) * 8);
                acc[ct] = __builtin_amdgcn_mfma_f32_16x16x32_bf16(wv, afr[kc], acc[ct], 0, 0, 0);
            }
        // D[feat][node]: lane owns node (t*16+m), feats ct*16+q*4 .. +3
        const size_t nodeoff = (size_t)(t * 16 + m) * 128;
        #pragma unroll
        for (int ct = 0; ct < 8; ++ct) {
            short4v o;
            o.x = f2bf(acc[ct][0]);
            o.y = f2bf(acc[ct][1]);
            o.z = f2bf(acc[ct][2]);
            o.w = f2bf(acc[ct][3]);
            *(short4v*)(outp + nodeoff + ct * 16 + q * 4) = o;
        }
    };

    if constexpr (F32IN) {
        float raw[KC][8];
        short8 afr[KC];
        // issue the loads only — no consumer, stays in flight
        auto load_raw = [&](int tile) {
            const float* xr = (const float*)inv + (size_t)(tile * 16 + m) * KSRC;
            #pragma unroll
            for (int kc = 0; kc < KC; ++kc) {
                const int k0 = kc * 32 + q * 8;
                #pragma unroll
                for (int p = 0; p < 4; ++p) {
                    const int k = k0 + 2 * p;
                    if (k + 2 <= KSRC) {          // KSRC even: pairs never straddle
                        f32x2 tv = *(const f32x2*)(xr + k);
                        raw[kc][2 * p] = tv.x; raw[kc][2 * p + 1] = tv.y;
                    } else {
                        raw[kc][2 * p] = 0.f; raw[kc][2 * p + 1] = 0.f;
                    }
                }
            }
        };
        auto cvt = [&]() {
            #pragma unroll
            for (int kc = 0; kc < KC; ++kc) {
                short8 a;
                #pragma unroll
                for (int j = 0; j < 8; ++j) a[j] = f2bf(raw[kc][j]);
                afr[kc] = a;
            }
        };

        load_raw(gw);
        for (int t = gw; t < NTILE; t += NW) {
            cvt();                                  // consume prev loads
            const int tn = t + NW;
            if (tn < NTILE) load_raw(tn);           // next loads in flight
            tile_mma(t, afr);                       // MFMAs hide them
        }
    } else {
        short8 fA[KC], fB[KC];
        auto load_to = [&](int tile, short8* b) {
            const short* xr = (const short*)inv + (size_t)(tile * 16 + m) * KSRC;
            #pragma unroll
            for (int kc = 0; kc < KC; ++kc)
                b[kc] = *(const short8*)(xr + kc * 32 + q * 8);
        };

        load_to(gw, fA);
        for (int t = gw; t < NTILE; t += NW) {
            const int tn = t + NW;
            if (tn < NTILE) load_to(tn, fB);        // in flight during MFMAs
            tile_mma(t, fA);
            #pragma unroll
            for (int kc = 0; kc < KC; ++kc) fA[kc] = fB[kc];
        }
    }
}

// ---------------- gather aggregation, FEATURE-SPLIT (64 feats per pass) ----------
// Two sequential launches (half=0,1) keep the random-read hot set at 51.2 MB so
// re-reads hit the 256 MB L3 instead of HBM.
// 8 lanes/node, 32 nodes/block: each lane covers 8 feats (16B contiguous loads,
// 128B fully-used line per row read).
// POOL=false: out[n] = relu(bias + hw[n]*dinv^2 + sum_s hw[s]*norm) -> agg (bf16)
// POOL=true : same value, but instead of writing agg, block-reduce max per graph
//             (nodes are batch-sorted; <=2 graphs per 32-node block) and
//             atomicMax into pool (f32-as-int; valid since values >= 0).
template<bool POOL>
__global__ __launch_bounds__(256) void k_gather_half(
    const unsigned short* __restrict__ hw, unsigned short* __restrict__ agg,
    const int* __restrict__ row_start, const int2* __restrict__ csr_ev,
    const float* __restrict__ dinv, const float* __restrict__ bias,
    const int* __restrict__ batch, int* __restrict__ pool, int half)
{
    const int n  = blockIdx.x * 32 + (threadIdx.x >> 3);
    const int c8 = half * 64 + (threadIdx.x & 7) * 8;     // feature base
    const float dv = dinv[n];
    const float d2 = dv * dv;

    float acc[8];
    {
        const short8 sv = *(const short8*)(hw + (size_t)n * HDIM + c8);
        #pragma unroll
        for (int j = 0; j < 8; ++j)
            acc[j] = fmaf(bf2f((unsigned short)sv[j]), d2, bias[c8 + j]);
    }

    const int s0 = row_start[n], s1 = row_start[n + 1];
    int i = s0;
    for (; i + 3 < s1; i += 4) {
        const int2 e0 = csr_ev[i];
        const int2 e1 = csr_ev[i + 1];
        const int2 e2 = csr_ev[i + 2];
        const int2 e3 = csr_ev[i + 3];
        const short8 r0 = *(const short8*)(hw + (size_t)e0.x * HDIM + c8);
        const short8 r1 = *(const short8*)(hw + (size_t)e1.x * HDIM + c8);
        const short8 r2 = *(const short8*)(hw + (size_t)e2.x * HDIM + c8);
        const short8 r3 = *(const short8*)(hw + (size_t)e3.x * HDIM + c8);
        const float w0 = __builtin_bit_cast(float, e0.y);
        const float w1 = __builtin_bit_cast(float, e1.y);
        const float w2 = __builtin_bit_cast(float, e2.y);
        const float w3 = __builtin_bit_cast(float, e3.y);
        #pragma unroll
        for (int j = 0; j < 8; ++j) acc[j] = fmaf(bf2f((unsigned short)r0[j]), w0, acc[j]);
        #pragma unroll
        for (int j = 0; j < 8; ++j) acc[j] = fmaf(bf2f((unsigned short)r1[j]), w1, acc[j]);
        #pragma unroll
        for (int j = 0; j < 8; ++j) acc[j] = fmaf(bf2f((unsigned short)r2[j]), w2, acc[j]);
        #pragma unroll
        for (int j = 0; j < 8; ++j) acc[j] = fmaf(bf2f((unsigned short)r3[j]), w3, acc[j]);
    }
    for (; i < s1; ++i) {
        const int2 e0 = csr_ev[i];
        const short8 r0 = *(const short8*)(hw + (size_t)e0.x * HDIM + c8);
        const float w0 = __builtin_bit_cast(float, e0.y);
        #pragma unroll
        for (int j = 0; j < 8; ++j) acc[j] = fmaf(bf2f((unsigned short)r0[j]), w0, acc[j]);
    }

    if constexpr (!POOL) {
        short8 o;
        #pragma unroll
        for (int j = 0; j < 8; ++j) o[j] = f2bf(fmaxf(acc[j], 0.f));
        __builtin_nontemporal_store(o, (short8*)(agg + (size_t)n * HDIM + c8));
    } else {
        // ---- fused graph max-pool (replaces agg write + k_pool) ----
        // relu is implicit: invalid slots masked to 0 and pool init'd to 0.
        const int gbase = batch[blockIdx.x * 32];           // uniform broadcast
        const int glast = batch[blockIdx.x * 32 + 31];      // uniform broadcast
        const int idx   = batch[n] - gbase;                 // 0 or 1

        float red[2][8];
        #pragma unroll
        for (int s = 0; s < 2; ++s)
            #pragma unroll
            for (int j = 0; j < 8; ++j)
                red[s][j] = (idx == s) ? fmaxf(acc[j], 0.f) : 0.f;

        // butterfly max across the 8 node-slots of the wave (bits 3..5 of lane)
        #pragma unroll
        for (int msk = 8; msk <= 32; msk <<= 1)
            #pragma unroll
            for (int s = 0; s < 2; ++s)
                #pragma unroll
                for (int j = 0; j < 8; ++j)
                    red[s][j] = fmaxf(red[s][j], __shfl_xor(red[s][j], msk));

        __shared__ float sm[4][2][64];
        const int wid  = threadIdx.x >> 6;
        const int lane = threadIdx.x & 63;
        if (lane < 8) {
            #pragma unroll
            for (int s = 0; s < 2; ++s)
                #pragma unroll
                for (int j = 0; j < 8; ++j)
                    sm[wid][s][lane * 8 + j] = red[s][j];
        }
        __syncthreads();
        if (threadIdx.x < 128) {
            const int s = threadIdx.x >> 6;      // graph slot
            const int f = threadIdx.x & 63;      // feature within half
            if (s == 0 || glast != gbase) {
                float m = fmaxf(fmaxf(sm[0][s][f], sm[1][s][f]),
                                fmaxf(sm[2][s][f], sm[3][s][f]));
                atomicMax(pool + (size_t)(gbase + s) * HDIM + half * 64 + f,
                          __builtin_bit_cast(int, m));
            }
        }
    }
}

// ---------------- f32 register-blocked GEMM (FF head only, tiny) ----------------
template<int K, int NC, bool OUT_RELU_BIAS>
__global__ __launch_bounds__(256) void k_gemm(
    const float* __restrict__ in, const float* __restrict__ W,
    const float* __restrict__ out_bias, float* __restrict__ out0, int M)
{
    constexpr int BK = 32;
    constexpr int TC = NC / 8;
    constexpr int TR = 256 / TC;
    constexpr int ROWS = TR * 8;
    constexpr int XST = ROWS + 4;

    __shared__ float xs[BK][XST];
    __shared__ float ws[BK][NC];

    const int tid = threadIdx.x;
    const int tc  = tid % TC;
    const int tr  = tid / TC;
    const int row0 = blockIdx.x * ROWS;

    float acc[8][8];
    #pragma unroll
    for (int i = 0; i < 8; ++i)
        #pragma unroll
        for (int j = 0; j < 8; ++j) acc[i][j] = 0.f;

    for (int k0 = 0; k0 < K; k0 += BK) {
        {
            constexpr int TASKS = BK * NC / 4;
            #pragma unroll
            for (int it = 0; it < TASKS / 256; ++it) {
                int t  = it * 256 + tid;
                int wk = t / (NC / 4);
                int wc = (t % (NC / 4)) * 4;
                *(float4*)(&ws[wk][wc]) = *(const float4*)(W + (size_t)(k0 + wk) * NC + wc);
            }
        }
        {
            constexpr int TASKS = ROWS * BK / 4;
            #pragma unroll
            for (int it = 0; it < TASKS / 256; ++it) {
                int t   = it * 256 + tid;
                int r   = t / (BK / 4);
                int kq  = (t % (BK / 4)) * 4;
                float4 x4 = *(const float4*)(in + (size_t)(row0 + r) * K + k0 + kq);
                xs[kq + 0][r] = x4.x; xs[kq + 1][r] = x4.y;
                xs[kq + 2][r] = x4.z; xs[kq + 3][r] = x4.w;
            }
        }
        __syncthreads();
        #pragma unroll 8
        for (int kk = 0; kk < BK; ++kk) {
            float a[8], b[8];
            #pragma unroll
            for (int i = 0; i < 8; ++i) a[i] = xs[kk][tr * 8 + i];
            #pragma unroll
            for (int j = 0; j < 8; ++j) b[j] = ws[kk][tc * 8 + j];
            #pragma unroll
            for (int i = 0; i < 8; ++i)
                #pragma unroll
                for (int j = 0; j < 8; ++j)
                    acc[i][j] = fmaf(a[i], b[j], acc[i][j]);
        }
        __syncthreads();
    }

    #pragma unroll
    for (int i = 0; i < 8; ++i) {
        const int row = row0 + tr * 8 + i;
        #pragma unroll
        for (int jq = 0; jq < 2; ++jq) {
            const int col = tc * 8 + jq * 4;
            float4 v;
            v.x = acc[i][jq * 4 + 0]; v.y = acc[i][jq * 4 + 1];
            v.z = acc[i][jq * 4 + 2]; v.w = acc[i][jq * 4 + 3];
            if constexpr (OUT_RELU_BIAS) {
                const float4 bb = *(const float4*)(out_bias + col);
                v.x = fmaxf(v.x + bb.x, 0.f); v.y = fmaxf(v.y + bb.y, 0.f);
                v.z = fmaxf(v.z + bb.z, 0.f); v.w = fmaxf(v.w + bb.w, 0.f);
            }
            *(float4*)(out0 + (size_t)row * NC + col) = v;
        }
    }
}

extern "C" void kernel_launch(void* const* d_in, const int* in_sizes, int n_in,
                              void* d_out, int out_size, void* d_ws, size_t ws_size,
                              hipStream_t stream) {
    const float* x    = (const float*)d_in[0];
    const int*   ei   = (const int*)d_in[1];
    const int*   batch= (const int*)d_in[2];
    const float* W0   = (const float*)d_in[3];
    const float* b0   = (const float*)d_in[4];
    const float* W1   = (const float*)d_in[5];
    const float* b1   = (const float*)d_in[6];
    const float* Wf0  = (const float*)d_in[7];
    const float* bf0  = (const float*)d_in[8];
    const float* Wf1  = (const float*)d_in[9];
    const float* bf1  = (const float*)d_in[10];
    float* out = (float*)d_out;

    const int* srcI = ei;
    const int* dstI = ei + NEDGES;

    constexpr int SCAN_NBLK = (NATOMS + 1023) / 1024;   // 391

    // workspace layout — total ~227.2 MB (round-6 proven envelope).
    // rank ALIASES the start of aggB: rank's lifetime (degi -> fill) ends before the
    // first gather writes aggB. All blocks 64B-aligned.
    char* base = (char*)d_ws;
    unsigned short* hwA  = (unsigned short*)(base + 0);              // N*128 bf16 = 102,400,000
    unsigned short* aggB = (unsigned short*)(base + 102400000);      // N*128 bf16 = 102,400,000
    int*   rank      = (int*)(base + 102400000);                     // E ints (alias of aggB)
    float* dinv      = (float*)(base + 204800000);                   // N f32 = 1,600,000
    int*   row_start = (int*)(base + 206400000);                     // N+1 ints
    int2*  csr_ev    = (int2*)(base + 208000064);                    // E int2 = 12,800,000
    int*   blockSums = (int*)(base + 220800064);                     // 512 ints
    float* pool      = (float*)(base + 220802112);                   // G*128 f32 = 2,097,152
    float* ff0       = (float*)(base + 222899264);                   // G*256 f32 = 4,194,304
    short* wf0       = (short*)(base + 227093568);                   // 8*3*64*8 bf16 = 24,576 B
    short* wf1       = (short*)(base + 227118144);                   // 8*4*64*8 bf16 = 32,768 B

    // 1) degree (+rank) -> scan (+dinv) -> atomic-free CSR fill
    hipMemsetAsync(row_start, 0, (size_t)(NATOMS + 1) * sizeof(int), stream);
    hipMemsetAsync(pool, 0, (size_t)NGRAPH * HDIM * sizeof(float), stream);  // pool init (relu identity)
    k_degi<<<(NEDGES + 255) / 256, 256, 0, stream>>>(dstI, row_start, rank, NEDGES);
    k_scan1<<<SCAN_NBLK, 256, 0, stream>>>(row_start, blockSums, dinv, NATOMS);
    k_scan2<<<1, 512, 0, stream>>>(blockSums, SCAN_NBLK);
    k_scan3<<<SCAN_NBLK, 256, 0, stream>>>(row_start, blockSums, NATOMS, NEDGES);
    k_fill<<<(NEDGES + 255) / 256, 256, 0, stream>>>(srcI, dstI, row_start, rank,
                                                     csr_ev, dinv, NEDGES);

    // 2) pack weights into MFMA fragment order (bf16)
    k_packw<3, F_INN><<<8 * 3, 64, 0, stream>>>(W0, wf0);
    k_packw<4, HDIM><<<8 * 4, 64, 0, stream>>>(W1, wf1);

    // 3) layer 0: hw0 = x@W0 (bf16) ; gather -> relu(agg + b0) bf16
    //    gather runs as two sequential 64-feature passes (51.2 MB hot set -> L3-resident)
    k_gemm_mfma<3, true, F_INN><<<768, 256, 0, stream>>>(x, wf0, (short*)hwA, NATOMS);
    k_gather_half<false><<<NATOMS / 32, 256, 0, stream>>>(hwA, aggB, row_start, csr_ev,
                                                          dinv, b0, nullptr, nullptr, 0);
    k_gather_half<false><<<NATOMS / 32, 256, 0, stream>>>(hwA, aggB, row_start, csr_ev,
                                                          dinv, b0, nullptr, nullptr, 1);

    // 4) layer 1: hw1 = h@W1 (bf16) ; gather fused with graph max-pool (no agg write)
    k_gemm_mfma<4, false, HDIM><<<768, 256, 0, stream>>>(aggB, wf1, (short*)hwA, NATOMS);
    k_gather_half<true><<<NATOMS / 32, 256, 0, stream>>>(hwA, nullptr, row_start, csr_ev,
                                                         dinv, b1, batch, (int*)pool, 0);
    k_gather_half<true><<<NATOMS / 32, 256, 0, stream>>>(hwA, nullptr, row_start, csr_ev,
                                                         dinv, b1, batch, (int*)pool, 1);

    // 5) FF head (f32, tiny)
    k_gemm<HDIM, FF0D, true><<<NGRAPH / 64, 256, 0, stream>>>(pool, Wf0, bf0, ff0, NGRAPH);
    k_gemm<FF0D, FF1D, true><<<NGRAPH / 128, 256, 0, stream>>>(ff0, Wf1, bf1, out, NGRAPH);
}

// Round 4
// 661.120 us; speedup vs baseline: 1.3314x; 1.0265x over previous
//
#include <hip/hip_runtime.h>
#include <cstdint>
#include <cstddef>

// Problem constants (fixed by the reference)
#define NATOMS 400000
#define NEDGES 1600000
#define NGRAPH 4096
#define F_INN  78
#define HDIM   128
#define FF0D   256
#define FF1D   128

typedef __attribute__((ext_vector_type(8))) short short8;   // 8 bf16 (4 VGPRs)
typedef __attribute__((ext_vector_type(4))) short short4v;  // 4 bf16 (8B store)
typedef __attribute__((ext_vector_type(4))) float f32x4;
typedef __attribute__((ext_vector_type(2))) float f32x2;

// f32 -> bf16 round-to-nearest-even (bit-level)
static __device__ __forceinline__ short f2bf(float f) {
    unsigned u = __builtin_bit_cast(unsigned, f);
    unsigned r = (u + 0x7fffu + ((u >> 16) & 1u)) >> 16;
    return (short)r;
}
static __device__ __forceinline__ float bf2f(unsigned short u) {
    return __builtin_bit_cast(float, ((unsigned)u) << 16);
}

// ---------------- degree + per-edge rank (atomic return value) ----------------
__global__ __launch_bounds__(256) void k_degi(const int* __restrict__ dst,
                                              int* __restrict__ deg,
                                              int* __restrict__ rank, int E) {
    int e = blockIdx.x * 256 + threadIdx.x;
    if (e < E) rank[e] = atomicAdd(&deg[dst[e]], 1);
}

// ---------------- exclusive scan over N ints (3 kernels, in-place) ----------------
// scan1 also emits dinv = rsqrt(deg+1) (deg still intact at entry)
__global__ __launch_bounds__(256) void k_scan1(int* __restrict__ data,
                                               int* __restrict__ blockSums,
                                               float* __restrict__ dinv, int n) {
    __shared__ int ts[256];
    const int base = blockIdx.x * 1024 + threadIdx.x * 4;
    int v[4];
    #pragma unroll
    for (int j = 0; j < 4; ++j) v[j] = (base + j < n) ? data[base + j] : 0;
    #pragma unroll
    for (int j = 0; j < 4; ++j)
        if (base + j < n) dinv[base + j] = rsqrtf((float)v[j] + 1.0f);
    const int tot = v[0] + v[1] + v[2] + v[3];
    ts[threadIdx.x] = tot;
    __syncthreads();
    #pragma unroll
    for (int off = 1; off < 256; off <<= 1) {
        int t = (threadIdx.x >= off) ? ts[threadIdx.x - off] : 0;
        __syncthreads();
        ts[threadIdx.x] += t;
        __syncthreads();
    }
    int run = ts[threadIdx.x] - tot;
    #pragma unroll
    for (int j = 0; j < 4; ++j) {
        if (base + j < n) data[base + j] = run;
        run += v[j];
    }
    if (threadIdx.x == 255) blockSums[blockIdx.x] = ts[255];
}

__global__ __launch_bounds__(512) void k_scan2(int* __restrict__ blockSums, int nb) {
    __shared__ int ts[512];
    int v = (threadIdx.x < nb) ? blockSums[threadIdx.x] : 0;
    ts[threadIdx.x] = v;
    __syncthreads();
    #pragma unroll
    for (int off = 1; off < 512; off <<= 1) {
        int t = (threadIdx.x >= off) ? ts[threadIdx.x - off] : 0;
        __syncthreads();
        ts[threadIdx.x] += t;
        __syncthreads();
    }
    if (threadIdx.x < nb) blockSums[threadIdx.x] = ts[threadIdx.x] - v;
}

__global__ __launch_bounds__(256) void k_scan3(int* __restrict__ data,
                                               const int* __restrict__ blockSums,
                                               int n, int total) {
    const int off = blockSums[blockIdx.x];
    const int base = blockIdx.x * 1024 + threadIdx.x * 4;
    #pragma unroll
    for (int j = 0; j < 4; ++j)
        if (base + j < n) data[base + j] += off;
    if (blockIdx.x == 0 && threadIdx.x == 0) data[n] = total;
}

// ---------------- CSR fill: atomic-free (pos = row_start[d] + rank[e]) ----------
__global__ __launch_bounds__(256) void k_fill(const int* __restrict__ src,
                                              const int* __restrict__ dst,
                                              const int* __restrict__ row_start,
                                              const int* __restrict__ rank,
                                              int2* __restrict__ csr_ev,
                                              const float* __restrict__ dinv, int E) {
    int e = blockIdx.x * 256 + threadIdx.x;
    if (e >= E) return;
    int d = dst[e];
    int s = src[e];
    int pos = row_start[d] + rank[e];
    float norm = dinv[s] * dinv[d];
    csr_ev[pos] = make_int2(s, __builtin_bit_cast(int, norm));
}

// ---------------- weight pack: W [KSRC][128] f32 -> MFMA A-fragment order bf16 ----
// A[feat][k]: lane&15 = feat-within-tile ct, k = kc*32 + (lane>>4)*8 + j
template<int KC, int KSRC>
__global__ __launch_bounds__(64) void k_packw(const float* __restrict__ W,
                                              short* __restrict__ wf) {
    int t = blockIdx.x * 64 + threadIdx.x;      // t = f*64 + lane
    int f = t >> 6, lane = t & 63;
    int ct = f / KC, kc = f % KC;
    int n  = ct * 16 + (lane & 15);
    int k0 = kc * 32 + (lane >> 4) * 8;
    short8 o;
    #pragma unroll
    for (int j = 0; j < 8; ++j) {
        int k = k0 + j;
        float v = (k < KSRC) ? W[(size_t)k * 128 + n] : 0.f;
        o[j] = f2bf(v);
    }
    *(short8*)(wf + (size_t)t * 8) = o;
}

// ---------------- persistent MFMA GEMM: out[M,128] = in[M,KSRC] @ W (bf16 out) ----
// 1024 blocks; weights staged to LDS once. Wave-autonomous grid-stride tiles
// with 1-deep load prefetch (loads in flight across each MFMA block).
// D-store goes through a wave-private 4KB LDS tile with XOR swizzle
// (c ^= (row&7)<<4): acc is written as 8B short4 (swizzled, conflict-free),
// read back as 16B/lane, and stored to global as 4x contiguous 1KB
// dwordx4 bursts. This removes the 16-segment scatter of the direct
// D-fragment stores (128 -> 4 store transactions per tile).
template<int KC, bool F32IN, int KSRC>
__global__ __launch_bounds__(256) void k_gemm_mfma(
    const void* __restrict__ inv, const short* __restrict__ wfrag,
    short* __restrict__ outp, int M)
{
    constexpr int NFRAG = 8 * KC;               // fragments (ct x kc)
    __shared__ short lds_w[NFRAG * 64 * 8];     // KC=4: 32 KB, KC=3: 24 KB
    __shared__ __align__(16) char lds_st[4 * 4096];   // 4 waves x 16 rows x 256B

    const int tid = threadIdx.x;
    // ---- stage weight fragments into LDS once ----
    #pragma unroll
    for (int it = 0; it < NFRAG * 64 / 256; ++it) {
        int t = it * 256 + tid;
        *(short8*)(lds_w + (size_t)t * 8) = *(const short8*)(wfrag + (size_t)t * 8);
    }
    __syncthreads();

    const int lane = tid & 63;
    const int m = lane & 15, q = lane >> 4;
    const int wid = tid >> 6;
    const int gw = blockIdx.x * 4 + wid;            // global wave id
    const int NW = gridDim.x * 4;                   // total waves
    const int NTILE = M / 16;
    char* const st = lds_st + wid * 4096;           // wave-private store tile

    // compute one 16-row tile from fragments + store (LDS-transposed, coalesced)
    auto tile_mma = [&](int t, const short8* afr) {
        f32x4 acc[8];
        #pragma unroll
        for (int ct = 0; ct < 8; ++ct) acc[ct] = (f32x4){0.f, 0.f, 0.f, 0.f};
        #pragma unroll
        for (int kc = 0; kc < KC; ++kc)
            #pragma unroll
            for (int ct = 0; ct < 8; ++ct) {
                const short8 wv = *(const short8*)(lds_w + ((size_t)((ct * KC + kc) * 64 + lane)) * 8);
                acc[ct] = __builtin_amdgcn_mfma_f32_16x16x32_bf16(wv, afr[kc], acc[ct], 0, 0, 0);
            }
        // D[feat][node]: lane owns node (t*16+m), feats ct*16+q*4 .. +3.
        // 1) swizzled 8B writes into wave-private LDS tile (row = m)
        #pragma unroll
        for (int ct = 0; ct < 8; ++ct) {
            short4v o;
            o.x = f2bf(acc[ct][0]);
            o.y = f2bf(acc[ct][1]);
            o.z = f2bf(acc[ct][2]);
            o.w = f2bf(acc[ct][3]);
            const int c = (ct * 32 + q * 8) ^ ((m & 7) << 4);
            *(short4v*)(st + m * 256 + c) = o;
        }
        // 2) coalesced read-back: lane covers one 16B chunk; 4 bursts of 1KB
        #pragma unroll
        for (int p = 0; p < 4; ++p) {
            const int r = p * 4 + (lane >> 4);
            const int c = ((lane & 15) * 16) ^ ((r & 7) << 4);
            const short8 v = *(const short8*)(st + r * 256 + c);
            *(short8*)(outp + (size_t)(t * 16 + r) * 128 + (lane & 15) * 8) = v;
        }
    };

    if constexpr (F32IN) {
        float raw[KC][8];
        short8 afr[KC];
        // issue the loads only — no consumer, stays in flight
        auto load_raw = [&](int tile) {
            const float* xr = (const float*)inv + (size_t)(tile * 16 + m) * KSRC;
            #pragma unroll
            for (int kc = 0; kc < KC; ++kc) {
                const int k0 = kc * 32 + q * 8;
                #pragma unroll
                for (int p = 0; p < 4; ++p) {
                    const int k = k0 + 2 * p;
                    if (k + 2 <= KSRC) {          // KSRC even: pairs never straddle
                        f32x2 tv = *(const f32x2*)(xr + k);
                        raw[kc][2 * p] = tv.x; raw[kc][2 * p + 1] = tv.y;
                    } else {
                        raw[kc][2 * p] = 0.f; raw[kc][2 * p + 1] = 0.f;
                    }
                }
            }
        };
        auto cvt = [&]() {
            #pragma unroll
            for (int kc = 0; kc < KC; ++kc) {
                short8 a;
                #pragma unroll
                for (int j = 0; j < 8; ++j) a[j] = f2bf(raw[kc][j]);
                afr[kc] = a;
            }
        };

        load_raw(gw);
        for (int t = gw; t < NTILE; t += NW) {
            cvt();                                  // consume prev loads
            const int tn = t + NW;
            if (tn < NTILE) load_raw(tn);           // next loads in flight
            tile_mma(t, afr);                       // MFMAs hide them
        }
    } else {
        short8 fA[KC], fB[KC];
        auto load_to = [&](int tile, short8* b) {
            const short* xr = (const short*)inv + (size_t)(tile * 16 + m) * KSRC;
            #pragma unroll
            for (int kc = 0; kc < KC; ++kc)
                b[kc] = *(const short8*)(xr + kc * 32 + q * 8);
        };

        load_to(gw, fA);
        for (int t = gw; t < NTILE; t += NW) {
            const int tn = t + NW;
            if (tn < NTILE) load_to(tn, fB);        // in flight during MFMAs
            tile_mma(t, fA);
            #pragma unroll
            for (int kc = 0; kc < KC; ++kc) fA[kc] = fB[kc];
        }
    }
}

// ---------------- gather aggregation, FEATURE-SPLIT (64 feats per pass) ----------
// Two sequential launches (half=0,1) keep the random-read hot set at 51.2 MB so
// re-reads hit the 256 MB L3 instead of HBM.
// 8 lanes/node, 32 nodes/block: each lane covers 8 feats (16B contiguous loads,
// 128B fully-used line per row read).
// POOL=false: out[n] = relu(bias + hw[n]*dinv^2 + sum_s hw[s]*norm) -> agg (bf16)
// POOL=true : same value, but instead of writing agg, block-reduce max per graph
//             (nodes are batch-sorted; <=2 graphs per 32-node block) and
//             atomicMax into pool (f32-as-int; valid since values >= 0).
template<bool POOL>
__global__ __launch_bounds__(256) void k_gather_half(
    const unsigned short* __restrict__ hw, unsigned short* __restrict__ agg,
    const int* __restrict__ row_start, const int2* __restrict__ csr_ev,
    const float* __restrict__ dinv, const float* __restrict__ bias,
    const int* __restrict__ batch, int* __restrict__ pool, int half)
{
    const int n  = blockIdx.x * 32 + (threadIdx.x >> 3);
    const int c8 = half * 64 + (threadIdx.x & 7) * 8;     // feature base
    const float dv = dinv[n];
    const float d2 = dv * dv;

    float acc[8];
    {
        const short8 sv = *(const short8*)(hw + (size_t)n * HDIM + c8);
        #pragma unroll
        for (int j = 0; j < 8; ++j)
            acc[j] = fmaf(bf2f((unsigned short)sv[j]), d2, bias[c8 + j]);
    }

    const int s0 = row_start[n], s1 = row_start[n + 1];
    int i = s0;
    for (; i + 3 < s1; i += 4) {
        const int2 e0 = csr_ev[i];
        const int2 e1 = csr_ev[i + 1];
        const int2 e2 = csr_ev[i + 2];
        const int2 e3 = csr_ev[i + 3];
        const short8 r0 = *(const short8*)(hw + (size_t)e0.x * HDIM + c8);
        const short8 r1 = *(const short8*)(hw + (size_t)e1.x * HDIM + c8);
        const short8 r2 = *(const short8*)(hw + (size_t)e2.x * HDIM + c8);
        const short8 r3 = *(const short8*)(hw + (size_t)e3.x * HDIM + c8);
        const float w0 = __builtin_bit_cast(float, e0.y);
        const float w1 = __builtin_bit_cast(float, e1.y);
        const float w2 = __builtin_bit_cast(float, e2.y);
        const float w3 = __builtin_bit_cast(float, e3.y);
        #pragma unroll
        for (int j = 0; j < 8; ++j) acc[j] = fmaf(bf2f((unsigned short)r0[j]), w0, acc[j]);
        #pragma unroll
        for (int j = 0; j < 8; ++j) acc[j] = fmaf(bf2f((unsigned short)r1[j]), w1, acc[j]);
        #pragma unroll
        for (int j = 0; j < 8; ++j) acc[j] = fmaf(bf2f((unsigned short)r2[j]), w2, acc[j]);
        #pragma unroll
        for (int j = 0; j < 8; ++j) acc[j] = fmaf(bf2f((unsigned short)r3[j]), w3, acc[j]);
    }
    for (; i < s1; ++i) {
        const int2 e0 = csr_ev[i];
        const short8 r0 = *(const short8*)(hw + (size_t)e0.x * HDIM + c8);
        const float w0 = __builtin_bit_cast(float, e0.y);
        #pragma unroll
        for (int j = 0; j < 8; ++j) acc[j] = fmaf(bf2f((unsigned short)r0[j]), w0, acc[j]);
    }

    if constexpr (!POOL) {
        short8 o;
        #pragma unroll
        for (int j = 0; j < 8; ++j) o[j] = f2bf(fmaxf(acc[j], 0.f));
        __builtin_nontemporal_store(o, (short8*)(agg + (size_t)n * HDIM + c8));
    } else {
        // ---- fused graph max-pool (replaces agg write + k_pool) ----
        // relu is implicit: invalid slots masked to 0 and pool init'd to 0.
        const int gbase = batch[blockIdx.x * 32];           // uniform broadcast
        const int glast = batch[blockIdx.x * 32 + 31];      // uniform broadcast
        const int idx   = batch[n] - gbase;                 // 0 or 1

        float red[2][8];
        #pragma unroll
        for (int s = 0; s < 2; ++s)
            #pragma unroll
            for (int j = 0; j < 8; ++j)
                red[s][j] = (idx == s) ? fmaxf(acc[j], 0.f) : 0.f;

        // butterfly max across the 8 node-slots of the wave (bits 3..5 of lane)
        #pragma unroll
        for (int msk = 8; msk <= 32; msk <<= 1)
            #pragma unroll
            for (int s = 0; s < 2; ++s)
                #pragma unroll
                for (int j = 0; j < 8; ++j)
                    red[s][j] = fmaxf(red[s][j], __shfl_xor(red[s][j], msk));

        __shared__ float sm[4][2][64];
        const int wid  = threadIdx.x >> 6;
        const int lane = threadIdx.x & 63;
        if (lane < 8) {
            #pragma unroll
            for (int s = 0; s < 2; ++s)
                #pragma unroll
                for (int j = 0; j < 8; ++j)
                    sm[wid][s][lane * 8 + j] = red[s][j];
        }
        __syncthreads();
        if (threadIdx.x < 128) {
            const int s = threadIdx.x >> 6;      // graph slot
            const int f = threadIdx.x & 63;      // feature within half
            if (s == 0 || glast != gbase) {
                float m = fmaxf(fmaxf(sm[0][s][f], sm[1][s][f]),
                                fmaxf(sm[2][s][f], sm[3][s][f]));
                atomicMax(pool + (size_t)(gbase + s) * HDIM + half * 64 + f,
                          __builtin_bit_cast(int, m));
            }
        }
    }
}

// ---------------- f32 register-blocked GEMM (FF head only, tiny) ----------------
template<int K, int NC, bool OUT_RELU_BIAS>
__global__ __launch_bounds__(256) void k_gemm(
    const float* __restrict__ in, const float* __restrict__ W,
    const float* __restrict__ out_bias, float* __restrict__ out0, int M)
{
    constexpr int BK = 32;
    constexpr int TC = NC / 8;
    constexpr int TR = 256 / TC;
    constexpr int ROWS = TR * 8;
    constexpr int XST = ROWS + 4;

    __shared__ float xs[BK][XST];
    __shared__ float ws[BK][NC];

    const int tid = threadIdx.x;
    const int tc  = tid % TC;
    const int tr  = tid / TC;
    const int row0 = blockIdx.x * ROWS;

    float acc[8][8];
    #pragma unroll
    for (int i = 0; i < 8; ++i)
        #pragma unroll
        for (int j = 0; j < 8; ++j) acc[i][j] = 0.f;

    for (int k0 = 0; k0 < K; k0 += BK) {
        {
            constexpr int TASKS = BK * NC / 4;
            #pragma unroll
            for (int it = 0; it < TASKS / 256; ++it) {
                int t  = it * 256 + tid;
                int wk = t / (NC / 4);
                int wc = (t % (NC / 4)) * 4;
                *(float4*)(&ws[wk][wc]) = *(const float4*)(W + (size_t)(k0 + wk) * NC + wc);
            }
        }
        {
            constexpr int TASKS = ROWS * BK / 4;
            #pragma unroll
            for (int it = 0; it < TASKS / 256; ++it) {
                int t   = it * 256 + tid;
                int r   = t / (BK / 4);
                int kq  = (t % (BK / 4)) * 4;
                float4 x4 = *(const float4*)(in + (size_t)(row0 + r) * K + k0 + kq);
                xs[kq + 0][r] = x4.x; xs[kq + 1][r] = x4.y;
                xs[kq + 2][r] = x4.z; xs[kq + 3][r] = x4.w;
            }
        }
        __syncthreads();
        #pragma unroll 8
        for (int kk = 0; kk < BK; ++kk) {
            float a[8], b[8];
            #pragma unroll
            for (int i = 0; i < 8; ++i) a[i] = xs[kk][tr * 8 + i];
            #pragma unroll
            for (int j = 0; j < 8; ++j) b[j] = ws[kk][tc * 8 + j];
            #pragma unroll
            for (int i = 0; i < 8; ++i)
                #pragma unroll
                for (int j = 0; j < 8; ++j)
                    acc[i][j] = fmaf(a[i], b[j], acc[i][j]);
        }
        __syncthreads();
    }

    #pragma unroll
    for (int i = 0; i < 8; ++i) {
        const int row = row0 + tr * 8 + i;
        #pragma unroll
        for (int jq = 0; jq < 2; ++jq) {
            const int col = tc * 8 + jq * 4;
            float4 v;
            v.x = acc[i][jq * 4 + 0]; v.y = acc[i][jq * 4 + 1];
            v.z = acc[i][jq * 4 + 2]; v.w = acc[i][jq * 4 + 3];
            if constexpr (OUT_RELU_BIAS) {
                const float4 bb = *(const float4*)(out_bias + col);
                v.x = fmaxf(v.x + bb.x, 0.f); v.y = fmaxf(v.y + bb.y, 0.f);
                v.z = fmaxf(v.z + bb.z, 0.f); v.w = fmaxf(v.w + bb.w, 0.f);
            }
            *(float4*)(out0 + (size_t)row * NC + col) = v;
        }
    }
}

extern "C" void kernel_launch(void* const* d_in, const int* in_sizes, int n_in,
                              void* d_out, int out_size, void* d_ws, size_t ws_size,
                              hipStream_t stream) {
    const float* x    = (const float*)d_in[0];
    const int*   ei   = (const int*)d_in[1];
    const int*   batch= (const int*)d_in[2];
    const float* W0   = (const float*)d_in[3];
    const float* b0   = (const float*)d_in[4];
    const float* W1   = (const float*)d_in[5];
    const float* b1   = (const float*)d_in[6];
    const float* Wf0  = (const float*)d_in[7];
    const float* bf0  = (const float*)d_in[8];
    const float* Wf1  = (const float*)d_in[9];
    const float* bf1  = (const float*)d_in[10];
    float* out = (float*)d_out;

    const int* srcI = ei;
    const int* dstI = ei + NEDGES;

    constexpr int SCAN_NBLK = (NATOMS + 1023) / 1024;   // 391

    // workspace layout — total ~227.2 MB (round-6 proven envelope).
    // rank ALIASES the start of aggB: rank's lifetime (degi -> fill) ends before the
    // first gather writes aggB. All blocks 64B-aligned.
    char* base = (char*)d_ws;
    unsigned short* hwA  = (unsigned short*)(base + 0);              // N*128 bf16 = 102,400,000
    unsigned short* aggB = (unsigned short*)(base + 102400000);      // N*128 bf16 = 102,400,000
    int*   rank      = (int*)(base + 102400000);                     // E ints (alias of aggB)
    float* dinv      = (float*)(base + 204800000);                   // N f32 = 1,600,000
    int*   row_start = (int*)(base + 206400000);                     // N+1 ints
    int2*  csr_ev    = (int2*)(base + 208000064);                    // E int2 = 12,800,000
    int*   blockSums = (int*)(base + 220800064);                     // 512 ints
    float* pool      = (float*)(base + 220802112);                   // G*128 f32 = 2,097,152
    float* ff0       = (float*)(base + 222899264);                   // G*256 f32 = 4,194,304
    short* wf0       = (short*)(base + 227093568);                   // 8*3*64*8 bf16 = 24,576 B
    short* wf1       = (short*)(base + 227118144);                   // 8*4*64*8 bf16 = 32,768 B

    // 1) degree (+rank) -> scan (+dinv) -> atomic-free CSR fill
    hipMemsetAsync(row_start, 0, (size_t)(NATOMS + 1) * sizeof(int), stream);
    hipMemsetAsync(pool, 0, (size_t)NGRAPH * HDIM * sizeof(float), stream);  // pool init (relu identity)
    k_degi<<<(NEDGES + 255) / 256, 256, 0, stream>>>(dstI, row_start, rank, NEDGES);
    k_scan1<<<SCAN_NBLK, 256, 0, stream>>>(row_start, blockSums, dinv, NATOMS);
    k_scan2<<<1, 512, 0, stream>>>(blockSums, SCAN_NBLK);
    k_scan3<<<SCAN_NBLK, 256, 0, stream>>>(row_start, blockSums, NATOMS, NEDGES);
    k_fill<<<(NEDGES + 255) / 256, 256, 0, stream>>>(srcI, dstI, row_start, rank,
                                                     csr_ev, dinv, NEDGES);

    // 2) pack weights into MFMA fragment order (bf16)
    k_packw<3, F_INN><<<8 * 3, 64, 0, stream>>>(W0, wf0);
    k_packw<4, HDIM><<<8 * 4, 64, 0, stream>>>(W1, wf1);

    // 3) layer 0: hw0 = x@W0 (bf16) ; gather -> relu(agg + b0) bf16
    //    gather runs as two sequential 64-feature passes (51.2 MB hot set -> L3-resident)
    k_gemm_mfma<3, true, F_INN><<<1024, 256, 0, stream>>>(x, wf0, (short*)hwA, NATOMS);
    k_gather_half<false><<<NATOMS / 32, 256, 0, stream>>>(hwA, aggB, row_start, csr_ev,
                                                          dinv, b0, nullptr, nullptr, 0);
    k_gather_half<false><<<NATOMS / 32, 256, 0, stream>>>(hwA, aggB, row_start, csr_ev,
                                                          dinv, b0, nullptr, nullptr, 1);

    // 4) layer 1: hw1 = h@W1 (bf16) ; gather fused with graph max-pool (no agg write)
    k_gemm_mfma<4, false, HDIM><<<1024, 256, 0, stream>>>(aggB, wf1, (short*)hwA, NATOMS);
    k_gather_half<true><<<NATOMS / 32, 256, 0, stream>>>(hwA, nullptr, row_start, csr_ev,
                                                         dinv, b1, batch, (int*)pool, 0);
    k_gather_half<true><<<NATOMS / 32, 256, 0, stream>>>(hwA, nullptr, row_start, csr_ev,
                                                         dinv, b1, batch, (int*)pool, 1);

    // 5) FF head (f32, tiny)
    k_gemm<HDIM, FF0D, true><<<NGRAPH / 64, 256, 0, stream>>>(pool, Wf0, bf0, ff0, NGRAPH);
    k_gemm<FF0D, FF1D, true><<<NGRAPH / 128, 256, 0, stream>>>(ff0, Wf1, bf1, out, NGRAPH);
}

// Round 5
// 650.135 us; speedup vs baseline: 1.3539x; 1.0169x over previous
//
#include <hip/hip_runtime.h>
#include <cstdint>
#include <cstddef>

// Problem constants (fixed by the reference)
#define NATOMS 400000
#define NEDGES 1600000
#define NGRAPH 4096
#define F_INN  78
#define HDIM   128
#define FF0D   256
#define FF1D   128

// layer-0 aggregated-input row: 78 feats + slot78=1.0 (bias) + slot79=0, bf16
#define XPAD   80

typedef __attribute__((ext_vector_type(8))) short short8;   // 8 bf16 (4 VGPRs)
typedef __attribute__((ext_vector_type(4))) short short4v;  // 4 bf16 (8B store)
typedef __attribute__((ext_vector_type(4))) float f32x4;
typedef __attribute__((ext_vector_type(2))) float f32x2;

// f32 -> bf16 round-to-nearest-even (bit-level)
static __device__ __forceinline__ short f2bf(float f) {
    unsigned u = __builtin_bit_cast(unsigned, f);
    unsigned r = (u + 0x7fffu + ((u >> 16) & 1u)) >> 16;
    return (short)r;
}
static __device__ __forceinline__ float bf2f(unsigned short u) {
    return __builtin_bit_cast(float, ((unsigned)u) << 16);
}

// ---------------- degree + per-edge rank (atomic return value) ----------------
__global__ __launch_bounds__(256) void k_degi(const int* __restrict__ dst,
                                              int* __restrict__ deg,
                                              int* __restrict__ rank, int E) {
    int e = blockIdx.x * 256 + threadIdx.x;
    if (e < E) rank[e] = atomicAdd(&deg[dst[e]], 1);
}

// ---------------- exclusive scan over N ints (3 kernels, in-place) ----------------
// scan1 also emits dinv = rsqrt(deg+1) (deg still intact at entry)
__global__ __launch_bounds__(256) void k_scan1(int* __restrict__ data,
                                               int* __restrict__ blockSums,
                                               float* __restrict__ dinv, int n) {
    __shared__ int ts[256];
    const int base = blockIdx.x * 1024 + threadIdx.x * 4;
    int v[4];
    #pragma unroll
    for (int j = 0; j < 4; ++j) v[j] = (base + j < n) ? data[base + j] : 0;
    #pragma unroll
    for (int j = 0; j < 4; ++j)
        if (base + j < n) dinv[base + j] = rsqrtf((float)v[j] + 1.0f);
    const int tot = v[0] + v[1] + v[2] + v[3];
    ts[threadIdx.x] = tot;
    __syncthreads();
    #pragma unroll
    for (int off = 1; off < 256; off <<= 1) {
        int t = (threadIdx.x >= off) ? ts[threadIdx.x - off] : 0;
        __syncthreads();
        ts[threadIdx.x] += t;
        __syncthreads();
    }
    int run = ts[threadIdx.x] - tot;
    #pragma unroll
    for (int j = 0; j < 4; ++j) {
        if (base + j < n) data[base + j] = run;
        run += v[j];
    }
    if (threadIdx.x == 255) blockSums[blockIdx.x] = ts[255];
}

__global__ __launch_bounds__(512) void k_scan2(int* __restrict__ blockSums, int nb) {
    __shared__ int ts[512];
    int v = (threadIdx.x < nb) ? blockSums[threadIdx.x] : 0;
    ts[threadIdx.x] = v;
    __syncthreads();
    #pragma unroll
    for (int off = 1; off < 512; off <<= 1) {
        int t = (threadIdx.x >= off) ? ts[threadIdx.x - off] : 0;
        __syncthreads();
        ts[threadIdx.x] += t;
        __syncthreads();
    }
    if (threadIdx.x < nb) blockSums[threadIdx.x] = ts[threadIdx.x] - v;
}

__global__ __launch_bounds__(256) void k_scan3(int* __restrict__ data,
                                               const int* __restrict__ blockSums,
                                               int n, int total) {
    const int off = blockSums[blockIdx.x];
    const int base = blockIdx.x * 1024 + threadIdx.x * 4;
    #pragma unroll
    for (int j = 0; j < 4; ++j)
        if (base + j < n) data[base + j] += off;
    if (blockIdx.x == 0 && threadIdx.x == 0) data[n] = total;
}

// ---------------- CSR fill: atomic-free (pos = row_start[d] + rank[e]) ----------
__global__ __launch_bounds__(256) void k_fill(const int* __restrict__ src,
                                              const int* __restrict__ dst,
                                              const int* __restrict__ row_start,
                                              const int* __restrict__ rank,
                                              int2* __restrict__ csr_ev,
                                              const float* __restrict__ dinv, int E) {
    int e = blockIdx.x * 256 + threadIdx.x;
    if (e >= E) return;
    int d = dst[e];
    int s = src[e];
    int pos = row_start[d] + rank[e];
    float norm = dinv[s] * dinv[d];
    csr_ev[pos] = make_int2(s, __builtin_bit_cast(int, norm));
}

// ---------------- weight pack: W [KSRC][128] f32 -> MFMA A-fragment order bf16 ----
// A[feat][k]: lane&15 = feat-within-tile ct, k = kc*32 + (lane>>4)*8 + j
// If BIASROW: k == KSRC takes bias[n] (input rows carry constant 1.0 there).
template<int KC, int KSRC, bool BIASROW>
__global__ __launch_bounds__(64) void k_packw(const float* __restrict__ W,
                                              const float* __restrict__ b,
                                              short* __restrict__ wf) {
    int t = blockIdx.x * 64 + threadIdx.x;      // t = f*64 + lane
    int f = t >> 6, lane = t & 63;
    int ct = f / KC, kc = f % KC;
    int n  = ct * 16 + (lane & 15);
    int k0 = kc * 32 + (lane >> 4) * 8;
    short8 o;
    #pragma unroll
    for (int j = 0; j < 8; ++j) {
        int k = k0 + j;
        float v = 0.f;
        if (k < KSRC) v = W[(size_t)k * 128 + n];
        else if (BIASROW && k == KSRC) v = b[n];
        o[j] = f2bf(v);
    }
    *(short8*)(wf + (size_t)t * 8) = o;
}

// ---------------- x pack: [N][78] f32 -> [N][80] bf16 (slots 78,79 zero) --------
__global__ __launch_bounds__(256) void k_packx(const float* __restrict__ x,
                                               unsigned short* __restrict__ xb) {
    int t = blockIdx.x * 256 + threadIdx.x;     // N*20 tasks, 4 shorts each
    if (t >= NATOMS * 20) return;
    int n = t / 20, g = t % 20;
    const float* xr = x + (size_t)n * F_INN + g * 4;
    short4v o;
    if (g < 19) {
        f32x2 a = *(const f32x2*)(xr);
        f32x2 b = *(const f32x2*)(xr + 2);
        o.x = f2bf(a.x); o.y = f2bf(a.y); o.z = f2bf(b.x); o.w = f2bf(b.y);
    } else {                                    // feats 76,77 + two zero pads
        f32x2 a = *(const f32x2*)(xr);
        o.x = f2bf(a.x); o.y = f2bf(a.y); o.z = 0; o.w = 0;
    }
    *(short4v*)(xb + (size_t)n * XPAD + g * 4) = o;
}

// ---------------- layer-0 pre-aggregation over raw features (80-slot rows) ------
// aggx[n] = dinv[n]^2 * xb[n] + sum_s norm(s,n) * xb[s]; slot78 := 1.0 (bias
// lane for the augmented GEMM), slot79 := 0. One pass: 64 MB hot set is
// L3-resident. 8 lanes/node: head short8 (16B) + tail uint (4B) per row.
__global__ __launch_bounds__(256) void k_gather78(
    const unsigned short* __restrict__ xb, unsigned short* __restrict__ aggx,
    const int* __restrict__ row_start, const int2* __restrict__ csr_ev,
    const float* __restrict__ dinv)
{
    const int n  = blockIdx.x * 32 + (threadIdx.x >> 3);
    const int l  = threadIdx.x & 7;
    const int c8 = l * 8;              // head feats c8..c8+7
    const int ct = 64 + l * 2;         // tail feats ct, ct+1
    const float dv = dinv[n];
    const float d2 = dv * dv;

    float acc[8], tacc0, tacc1;
    {
        const short8 sv = *(const short8*)(xb + (size_t)n * XPAD + c8);
        const unsigned tv = *(const unsigned*)(xb + (size_t)n * XPAD + ct);
        #pragma unroll
        for (int j = 0; j < 8; ++j) acc[j] = bf2f((unsigned short)sv[j]) * d2;
        tacc0 = bf2f((unsigned short)(tv & 0xffff)) * d2;
        tacc1 = bf2f((unsigned short)(tv >> 16)) * d2;
    }

    const int s0 = row_start[n], s1 = row_start[n + 1];
    int i = s0;
    for (; i + 3 < s1; i += 4) {
        const int2 e0 = csr_ev[i];
        const int2 e1 = csr_ev[i + 1];
        const int2 e2 = csr_ev[i + 2];
        const int2 e3 = csr_ev[i + 3];
        const short8 r0 = *(const short8*)(xb + (size_t)e0.x * XPAD + c8);
        const short8 r1 = *(const short8*)(xb + (size_t)e1.x * XPAD + c8);
        const short8 r2 = *(const short8*)(xb + (size_t)e2.x * XPAD + c8);
        const short8 r3 = *(const short8*)(xb + (size_t)e3.x * XPAD + c8);
        const unsigned t0 = *(const unsigned*)(xb + (size_t)e0.x * XPAD + ct);
        const unsigned t1 = *(const unsigned*)(xb + (size_t)e1.x * XPAD + ct);
        const unsigned t2 = *(const unsigned*)(xb + (size_t)e2.x * XPAD + ct);
        const unsigned t3 = *(const unsigned*)(xb + (size_t)e3.x * XPAD + ct);
        const float w0 = __builtin_bit_cast(float, e0.y);
        const float w1 = __builtin_bit_cast(float, e1.y);
        const float w2 = __builtin_bit_cast(float, e2.y);
        const float w3 = __builtin_bit_cast(float, e3.y);
        #pragma unroll
        for (int j = 0; j < 8; ++j) acc[j] = fmaf(bf2f((unsigned short)r0[j]), w0, acc[j]);
        #pragma unroll
        for (int j = 0; j < 8; ++j) acc[j] = fmaf(bf2f((unsigned short)r1[j]), w1, acc[j]);
        #pragma unroll
        for (int j = 0; j < 8; ++j) acc[j] = fmaf(bf2f((unsigned short)r2[j]), w2, acc[j]);
        #pragma unroll
        for (int j = 0; j < 8; ++j) acc[j] = fmaf(bf2f((unsigned short)r3[j]), w3, acc[j]);
        tacc0 = fmaf(bf2f((unsigned short)(t0 & 0xffff)), w0, tacc0);
        tacc1 = fmaf(bf2f((unsigned short)(t0 >> 16)),    w0, tacc1);
        tacc0 = fmaf(bf2f((unsigned short)(t1 & 0xffff)), w1, tacc0);
        tacc1 = fmaf(bf2f((unsigned short)(t1 >> 16)),    w1, tacc1);
        tacc0 = fmaf(bf2f((unsigned short)(t2 & 0xffff)), w2, tacc0);
        tacc1 = fmaf(bf2f((unsigned short)(t2 >> 16)),    w2, tacc1);
        tacc0 = fmaf(bf2f((unsigned short)(t3 & 0xffff)), w3, tacc0);
        tacc1 = fmaf(bf2f((unsigned short)(t3 >> 16)),    w3, tacc1);
    }
    for (; i < s1; ++i) {
        const int2 e0 = csr_ev[i];
        const short8 r0 = *(const short8*)(xb + (size_t)e0.x * XPAD + c8);
        const unsigned t0 = *(const unsigned*)(xb + (size_t)e0.x * XPAD + ct);
        const float w0 = __builtin_bit_cast(float, e0.y);
        #pragma unroll
        for (int j = 0; j < 8; ++j) acc[j] = fmaf(bf2f((unsigned short)r0[j]), w0, acc[j]);
        tacc0 = fmaf(bf2f((unsigned short)(t0 & 0xffff)), w0, tacc0);
        tacc1 = fmaf(bf2f((unsigned short)(t0 >> 16)),    w0, tacc1);
    }

    short8 o;
    #pragma unroll
    for (int j = 0; j < 8; ++j) o[j] = f2bf(acc[j]);
    *(short8*)(aggx + (size_t)n * XPAD + c8) = o;
    unsigned to;
    if (l == 7) to = 0x00003F80u;      // slot78 = bf16(1.0), slot79 = 0
    else {
        to = (unsigned)(unsigned short)f2bf(tacc0) |
             ((unsigned)(unsigned short)f2bf(tacc1) << 16);
    }
    *(unsigned*)(aggx + (size_t)n * XPAD + ct) = to;
}

// ---------------- persistent MFMA GEMM: out[M,128] = in[M,KSRC] @ W (bf16 out) ----
// 1024 blocks; weights staged to LDS once. Wave-autonomous grid-stride tiles
// with 1-deep load prefetch (loads in flight across each MFMA block).
// D-store goes through a wave-private 4KB LDS tile with XOR swizzle
// (c ^= (row&7)<<4): acc written as 8B short4 (conflict-free), read back
// 16B/lane, stored as 4x contiguous 1KB dwordx4 bursts.
// KSRC is also the input row stride (in shorts). RELU applies epilogue relu
// (bias arrives via the augmented k=KSRC-2 row for layer 0).
template<int KC, int KSRC, bool RELU>
__global__ __launch_bounds__(256) void k_gemm_mfma(
    const short* __restrict__ inv, const short* __restrict__ wfrag,
    short* __restrict__ outp, int M)
{
    constexpr int NFRAG = 8 * KC;               // fragments (ct x kc)
    __shared__ short lds_w[NFRAG * 64 * 8];     // KC=4: 32 KB, KC=3: 24 KB
    __shared__ __align__(16) char lds_st[4 * 4096];   // 4 waves x 16 rows x 256B

    const int tid = threadIdx.x;
    // ---- stage weight fragments into LDS once ----
    #pragma unroll
    for (int it = 0; it < NFRAG * 64 / 256; ++it) {
        int t = it * 256 + tid;
        *(short8*)(lds_w + (size_t)t * 8) = *(const short8*)(wfrag + (size_t)t * 8);
    }
    __syncthreads();

    const int lane = tid & 63;
    const int m = lane & 15, q = lane >> 4;
    const int wid = tid >> 6;
    const int gw = blockIdx.x * 4 + wid;            // global wave id
    const int NW = gridDim.x * 4;                   // total waves
    const int NTILE = M / 16;
    char* const st = lds_st + wid * 4096;           // wave-private store tile

    // compute one 16-row tile from fragments + store (LDS-transposed, coalesced)
    auto tile_mma = [&](int t, const short8* afr) {
        f32x4 acc[8];
        #pragma unroll
        for (int ct = 0; ct < 8; ++ct) acc[ct] = (f32x4){0.f, 0.f, 0.f, 0.f};
        #pragma unroll
        for (int kc = 0; kc < KC; ++kc)
            #pragma unroll
            for (int ct = 0; ct < 8; ++ct) {
                const short8 wv = *(const short8*)(lds_w + ((size_t)((ct * KC + kc) * 64 + lane)) * 8);
                acc[ct] = __builtin_amdgcn_mfma_f32_16x16x32_bf16(wv, afr[kc], acc[ct], 0, 0, 0);
            }
        // D[feat][node]: lane owns node (t*16+m), feats ct*16+q*4 .. +3.
        #pragma unroll
        for (int ct = 0; ct < 8; ++ct) {
            short4v o;
            float v0 = acc[ct][0], v1 = acc[ct][1], v2 = acc[ct][2], v3 = acc[ct][3];
            if constexpr (RELU) {
                v0 = fmaxf(v0, 0.f); v1 = fmaxf(v1, 0.f);
                v2 = fmaxf(v2, 0.f); v3 = fmaxf(v3, 0.f);
            }
            o.x = f2bf(v0); o.y = f2bf(v1); o.z = f2bf(v2); o.w = f2bf(v3);
            const int c = (ct * 32 + q * 8) ^ ((m & 7) << 4);
            *(short4v*)(st + m * 256 + c) = o;
        }
        #pragma unroll
        for (int p = 0; p < 4; ++p) {
            const int r = p * 4 + (lane >> 4);
            const int c = ((lane & 15) * 16) ^ ((r & 7) << 4);
            const short8 v = *(const short8*)(st + r * 256 + c);
            *(short8*)(outp + (size_t)(t * 16 + r) * 128 + (lane & 15) * 8) = v;
        }
    };

    short8 fA[KC], fB[KC];
    auto load_to = [&](int tile, short8* b) {
        const short* xr = inv + (size_t)(tile * 16 + m) * KSRC;
        #pragma unroll
        for (int kc = 0; kc < KC; ++kc) {
            const int k0 = kc * 32 + q * 8;
            short8 v = {0, 0, 0, 0, 0, 0, 0, 0};
            if (k0 + 8 <= KSRC) v = *(const short8*)(xr + k0);
            b[kc] = v;
        }
    };

    load_to(gw, fA);
    for (int t = gw; t < NTILE; t += NW) {
        const int tn = t + NW;
        if (tn < NTILE) load_to(tn, fB);        // in flight during MFMAs
        tile_mma(t, fA);
        #pragma unroll
        for (int kc = 0; kc < KC; ++kc) fA[kc] = fB[kc];
    }
}

// ---------------- gather aggregation + fused max-pool (layer 1 epilogue) --------
// Two sequential launches (half=0,1) keep the random-read hot set at 51.2 MB so
// re-reads hit the 256 MB L3 instead of HBM. 8 lanes/node, 32 nodes/block.
// val[n] = relu(bias + hw[n]*dinv^2 + sum_s hw[s]*norm); block-reduce max per
// graph (nodes batch-sorted; <=2 graphs per 32-node block), atomicMax into pool
// (f32-as-int; valid since values >= 0, pool init'd to 0).
__global__ __launch_bounds__(256) void k_gather_pool(
    const unsigned short* __restrict__ hw,
    const int* __restrict__ row_start, const int2* __restrict__ csr_ev,
    const float* __restrict__ dinv, const float* __restrict__ bias,
    const int* __restrict__ batch, int* __restrict__ pool, int half)
{
    const int n  = blockIdx.x * 32 + (threadIdx.x >> 3);
    const int c8 = half * 64 + (threadIdx.x & 7) * 8;     // feature base
    const float dv = dinv[n];
    const float d2 = dv * dv;

    float acc[8];
    {
        const short8 sv = *(const short8*)(hw + (size_t)n * HDIM + c8);
        #pragma unroll
        for (int j = 0; j < 8; ++j)
            acc[j] = fmaf(bf2f((unsigned short)sv[j]), d2, bias[c8 + j]);
    }

    const int s0 = row_start[n], s1 = row_start[n + 1];
    int i = s0;
    for (; i + 3 < s1; i += 4) {
        const int2 e0 = csr_ev[i];
        const int2 e1 = csr_ev[i + 1];
        const int2 e2 = csr_ev[i + 2];
        const int2 e3 = csr_ev[i + 3];
        const short8 r0 = *(const short8*)(hw + (size_t)e0.x * HDIM + c8);
        const short8 r1 = *(const short8*)(hw + (size_t)e1.x * HDIM + c8);
        const short8 r2 = *(const short8*)(hw + (size_t)e2.x * HDIM + c8);
        const short8 r3 = *(const short8*)(hw + (size_t)e3.x * HDIM + c8);
        const float w0 = __builtin_bit_cast(float, e0.y);
        const float w1 = __builtin_bit_cast(float, e1.y);
        const float w2 = __builtin_bit_cast(float, e2.y);
        const float w3 = __builtin_bit_cast(float, e3.y);
        #pragma unroll
        for (int j = 0; j < 8; ++j) acc[j] = fmaf(bf2f((unsigned short)r0[j]), w0, acc[j]);
        #pragma unroll
        for (int j = 0; j < 8; ++j) acc[j] = fmaf(bf2f((unsigned short)r1[j]), w1, acc[j]);
        #pragma unroll
        for (int j = 0; j < 8; ++j) acc[j] = fmaf(bf2f((unsigned short)r2[j]), w2, acc[j]);
        #pragma unroll
        for (int j = 0; j < 8; ++j) acc[j] = fmaf(bf2f((unsigned short)r3[j]), w3, acc[j]);
    }
    for (; i < s1; ++i) {
        const int2 e0 = csr_ev[i];
        const short8 r0 = *(const short8*)(hw + (size_t)e0.x * HDIM + c8);
        const float w0 = __builtin_bit_cast(float, e0.y);
        #pragma unroll
        for (int j = 0; j < 8; ++j) acc[j] = fmaf(bf2f((unsigned short)r0[j]), w0, acc[j]);
    }

    // ---- fused graph max-pool ----
    const int gbase = batch[blockIdx.x * 32];           // uniform broadcast
    const int glast = batch[blockIdx.x * 32 + 31];      // uniform broadcast
    const int idx   = batch[n] - gbase;                 // 0 or 1

    float red[2][8];
    #pragma unroll
    for (int s = 0; s < 2; ++s)
        #pragma unroll
        for (int j = 0; j < 8; ++j)
            red[s][j] = (idx == s) ? fmaxf(acc[j], 0.f) : 0.f;

    #pragma unroll
    for (int msk = 8; msk <= 32; msk <<= 1)
        #pragma unroll
        for (int s = 0; s < 2; ++s)
            #pragma unroll
            for (int j = 0; j < 8; ++j)
                red[s][j] = fmaxf(red[s][j], __shfl_xor(red[s][j], msk));

    __shared__ float sm[4][2][64];
    const int wid  = threadIdx.x >> 6;
    const int lane = threadIdx.x & 63;
    if (lane < 8) {
        #pragma unroll
        for (int s = 0; s < 2; ++s)
            #pragma unroll
            for (int j = 0; j < 8; ++j)
                sm[wid][s][lane * 8 + j] = red[s][j];
    }
    __syncthreads();
    if (threadIdx.x < 128) {
        const int s = threadIdx.x >> 6;      // graph slot
        const int f = threadIdx.x & 63;      // feature within half
        if (s == 0 || glast != gbase) {
            float m = fmaxf(fmaxf(sm[0][s][f], sm[1][s][f]),
                            fmaxf(sm[2][s][f], sm[3][s][f]));
            atomicMax(pool + (size_t)(gbase + s) * HDIM + half * 64 + f,
                      __builtin_bit_cast(int, m));
        }
    }
}

// ---------------- f32 register-blocked GEMM (FF head only, tiny) ----------------
template<int K, int NC, bool OUT_RELU_BIAS>
__global__ __launch_bounds__(256) void k_gemm(
    const float* __restrict__ in, const float* __restrict__ W,
    const float* __restrict__ out_bias, float* __restrict__ out0, int M)
{
    constexpr int BK = 32;
    constexpr int TC = NC / 8;
    constexpr int TR = 256 / TC;
    constexpr int ROWS = TR * 8;
    constexpr int XST = ROWS + 4;

    __shared__ float xs[BK][XST];
    __shared__ float ws[BK][NC];

    const int tid = threadIdx.x;
    const int tc  = tid % TC;
    const int tr  = tid / TC;
    const int row0 = blockIdx.x * ROWS;

    float acc[8][8];
    #pragma unroll
    for (int i = 0; i < 8; ++i)
        #pragma unroll
        for (int j = 0; j < 8; ++j) acc[i][j] = 0.f;

    for (int k0 = 0; k0 < K; k0 += BK) {
        {
            constexpr int TASKS = BK * NC / 4;
            #pragma unroll
            for (int it = 0; it < TASKS / 256; ++it) {
                int t  = it * 256 + tid;
                int wk = t / (NC / 4);
                int wc = (t % (NC / 4)) * 4;
                *(float4*)(&ws[wk][wc]) = *(const float4*)(W + (size_t)(k0 + wk) * NC + wc);
            }
        }
        {
            constexpr int TASKS = ROWS * BK / 4;
            #pragma unroll
            for (int it = 0; it < TASKS / 256; ++it) {
                int t   = it * 256 + tid;
                int r   = t / (BK / 4);
                int kq  = (t % (BK / 4)) * 4;
                float4 x4 = *(const float4*)(in + (size_t)(row0 + r) * K + k0 + kq);
                xs[kq + 0][r] = x4.x; xs[kq + 1][r] = x4.y;
                xs[kq + 2][r] = x4.z; xs[kq + 3][r] = x4.w;
            }
        }
        __syncthreads();
        #pragma unroll 8
        for (int kk = 0; kk < BK; ++kk) {
            float a[8], b[8];
            #pragma unroll
            for (int i = 0; i < 8; ++i) a[i] = xs[kk][tr * 8 + i];
            #pragma unroll
            for (int j = 0; j < 8; ++j) b[j] = ws[kk][tc * 8 + j];
            #pragma unroll
            for (int i = 0; i < 8; ++i)
                #pragma unroll
                for (int j = 0; j < 8; ++j)
                    acc[i][j] = fmaf(a[i], b[j], acc[i][j]);
        }
        __syncthreads();
    }

    #pragma unroll
    for (int i = 0; i < 8; ++i) {
        const int row = row0 + tr * 8 + i;
        #pragma unroll
        for (int jq = 0; jq < 2; ++jq) {
            const int col = tc * 8 + jq * 4;
            float4 v;
            v.x = acc[i][jq * 4 + 0]; v.y = acc[i][jq * 4 + 1];
            v.z = acc[i][jq * 4 + 2]; v.w = acc[i][jq * 4 + 3];
            if constexpr (OUT_RELU_BIAS) {
                const float4 bb = *(const float4*)(out_bias + col);
                v.x = fmaxf(v.x + bb.x, 0.f); v.y = fmaxf(v.y + bb.y, 0.f);
                v.z = fmaxf(v.z + bb.z, 0.f); v.w = fmaxf(v.w + bb.w, 0.f);
            }
            *(float4*)(out0 + (size_t)row * NC + col) = v;
        }
    }
}

extern "C" void kernel_launch(void* const* d_in, const int* in_sizes, int n_in,
                              void* d_out, int out_size, void* d_ws, size_t ws_size,
                              hipStream_t stream) {
    const float* x    = (const float*)d_in[0];
    const int*   ei   = (const int*)d_in[1];
    const int*   batch= (const int*)d_in[2];
    const float* W0   = (const float*)d_in[3];
    const float* b0   = (const float*)d_in[4];
    const float* W1   = (const float*)d_in[5];
    const float* b1   = (const float*)d_in[6];
    const float* Wf0  = (const float*)d_in[7];
    const float* bf0  = (const float*)d_in[8];
    const float* Wf1  = (const float*)d_in[9];
    const float* bf1  = (const float*)d_in[10];
    float* out = (float*)d_out;

    const int* srcI = ei;
    const int* dstI = ei + NEDGES;

    constexpr int SCAN_NBLK = (NATOMS + 1023) / 1024;   // 391

    // workspace layout — ~227.2 MB envelope, aggressive lifetime aliasing:
    //   aggx (64 MB)  aliases hwA   [0, 64M):  live gather78 -> GEMM-0;
    //                                hwA written by GEMM-1 (after GEMM-0 read).
    //   xb   (64 MB)  aliases aggB  [102.4M, 166.4M): live packx -> gather78;
    //                                aggB written by GEMM-0 (after xb dead).
    //   rank (6.4 MB) aliases aggB start: dead after k_fill, before packx.
    char* base = (char*)d_ws;
    unsigned short* hwA  = (unsigned short*)(base + 0);              // N*128 bf16
    unsigned short* aggx = (unsigned short*)(base + 0);              // N*80 bf16 (alias)
    unsigned short* aggB = (unsigned short*)(base + 102400000);      // N*128 bf16
    unsigned short* xb   = (unsigned short*)(base + 102400000);      // N*80 bf16 (alias)
    int*   rank      = (int*)(base + 102400000);                     // E ints (alias)
    float* dinv      = (float*)(base + 204800000);                   // N f32
    int*   row_start = (int*)(base + 206400000);                     // N+1 ints
    int2*  csr_ev    = (int2*)(base + 208000064);                    // E int2
    int*   blockSums = (int*)(base + 220800064);                     // 512 ints
    float* pool      = (float*)(base + 220802112);                   // G*128 f32
    float* ff0       = (float*)(base + 222899264);                   // G*256 f32
    short* wf0       = (short*)(base + 227093568);                   // 8*3*64*8 bf16
    short* wf1       = (short*)(base + 227118144);                   // 8*4*64*8 bf16

    // 1) degree (+rank) -> scan (+dinv) -> atomic-free CSR fill
    hipMemsetAsync(row_start, 0, (size_t)(NATOMS + 1) * sizeof(int), stream);
    hipMemsetAsync(pool, 0, (size_t)NGRAPH * HDIM * sizeof(float), stream);  // relu identity
    k_degi<<<(NEDGES + 255) / 256, 256, 0, stream>>>(dstI, row_start, rank, NEDGES);
    k_scan1<<<SCAN_NBLK, 256, 0, stream>>>(row_start, blockSums, dinv, NATOMS);
    k_scan2<<<1, 512, 0, stream>>>(blockSums, SCAN_NBLK);
    k_scan3<<<SCAN_NBLK, 256, 0, stream>>>(row_start, blockSums, NATOMS, NEDGES);
    k_fill<<<(NEDGES + 255) / 256, 256, 0, stream>>>(srcI, dstI, row_start, rank,
                                                     csr_ev, dinv, NEDGES);

    // 2) pack weights (W0 augmented: k=78 row carries b0) + pack x to bf16[80]
    k_packw<3, F_INN, true><<<8 * 3, 64, 0, stream>>>(W0, b0, wf0);
    k_packw<4, HDIM, false><<<8 * 4, 64, 0, stream>>>(W1, nullptr, wf1);
    k_packx<<<(NATOMS * 20 + 255) / 256, 256, 0, stream>>>(x, xb);

    // 3) layer 0, reassociated: aggx = A_hat @ xb (78-dim gather, one L3-resident
    //    pass), then aggB = relu(aggx_aug @ W0_aug)  [bias via slot 78]
    k_gather78<<<NATOMS / 32, 256, 0, stream>>>(xb, aggx, row_start, csr_ev, dinv);
    k_gemm_mfma<3, XPAD, true><<<1024, 256, 0, stream>>>((const short*)aggx, wf0,
                                                         (short*)aggB, NATOMS);

    // 4) layer 1: hw1 = aggB@W1 ; gather fused with bias+relu+graph max-pool
    k_gemm_mfma<4, HDIM, false><<<1024, 256, 0, stream>>>((const short*)aggB, wf1,
                                                          (short*)hwA, NATOMS);
    k_gather_pool<<<NATOMS / 32, 256, 0, stream>>>(hwA, row_start, csr_ev,
                                                   dinv, b1, batch, (int*)pool, 0);
    k_gather_pool<<<NATOMS / 32, 256, 0, stream>>>(hwA, row_start, csr_ev,
                                                   dinv, b1, batch, (int*)pool, 1);

    // 5) FF head (f32, tiny)
    k_gemm<HDIM, FF0D, true><<<NGRAPH / 64, 256, 0, stream>>>(pool, Wf0, bf0, ff0, NGRAPH);
    k_gemm<FF0D, FF1D, true><<<NGRAPH / 128, 256, 0, stream>>>(ff0, Wf1, bf1, out, NGRAPH);
}